// Round 7
// baseline (355.219 us; speedup 1.0000x reference)
//
#include <hip/hip_runtime.h>

#define N_    8
#define C_    256
#define K_    7
#define HID_  10
#define OUTC_ 60
#define S_    16384
#define BN_EPS 1e-5f

// ---- workspace layout (float offsets, all 16B-aligned) ----
#define OFF_PP     0        // pool partials: [n][sh][oct][64] = 8*2*32*64 = 32768
#define OFF_DP     32768    // den partials:  [n*32+t][8] = 2048
#define OFF_EB     34816    // 64
#define OFF_M2     34880    // 3392
#define OFF_WPT80  38272    // N*256*80 = 163840
#define OFF_ATT    202112   // N*K*S = 917504
#define OFF_PART   1119616  // 512*120 = 61440
#define OFF_SCL    1181056  // 64
#define OFF_SHF    1181120  // 64
// total 1181184 floats ~= 4.7 MB

#define GLDS(g, l) __builtin_amdgcn_global_load_lds( \
    (const __attribute__((address_space(1))) unsigned int*)(g), \
    (__attribute__((address_space(3))) unsigned int*)(l), 16, 0, 0)

__device__ __forceinline__ float4 f4max(float4 a, float4 b) {
    return make_float4(fmaxf(a.x,b.x), fmaxf(a.y,b.y), fmaxf(a.z,b.z), fmaxf(a.w,b.w));
}

// ---------------- kernel A0: class softmax (once per pixel) + den partials ----
__global__ void __launch_bounds__(256) k_att(
        const float* __restrict__ seg, float* __restrict__ att,
        float* __restrict__ dp) {
    int b = blockIdx.x;
    int lin = (b & 7) * 32 + (b >> 3);
    int n = lin >> 5, t = lin & 31;
    int tid = threadIdx.x;
    const float* sp = seg + (size_t)n * K_ * S_ + t * 512 + tid * 2;
    float* ap = att + (size_t)n * K_ * S_ + t * 512 + tid * 2;

    float2 e[K_];
    float mx = -1e30f, my = -1e30f;
#pragma unroll
    for (int k = 0; k < K_; k++) {
        e[k] = *(const float2*)(sp + (size_t)k * S_);
        mx = fmaxf(mx, e[k].x); my = fmaxf(my, e[k].y);
    }
    float sx = 0.f, sy = 0.f;
#pragma unroll
    for (int k = 0; k < K_; k++) {
        e[k].x = __expf(e[k].x - mx); sx += e[k].x;
        e[k].y = __expf(e[k].y - my); sy += e[k].y;
    }
    float ix = 1.f / sx, iy = 1.f / sy;
    float dsum[K_];
#pragma unroll
    for (int k = 0; k < K_; k++) {
        float2 a = make_float2(e[k].x * ix, e[k].y * iy);
        *(float2*)(ap + (size_t)k * S_) = a;
        dsum[k] = a.x + a.y;
    }
    __shared__ float red[4][K_];
    int lane = tid & 63, wv = tid >> 6;
#pragma unroll
    for (int k = 0; k < K_; k++) {
        float v = dsum[k];
        for (int off = 32; off; off >>= 1) v += __shfl_xor(v, off, 64);
        if (lane == 0) red[wv][k] = v;
    }
    __syncthreads();
    if (tid < K_)
        dp[((size_t)n * 32 + t) * 8 + tid] =
            red[0][tid] + red[1][tid] + red[2][tid] + red[3][tid];
}

// ---------------- kernel A1: pooling GEMM, 1-deep software pipeline ----------
__global__ void __launch_bounds__(256, 2) k_num(
        const float* __restrict__ fea, const float* __restrict__ att,
        float* __restrict__ pp) {
    int b = blockIdx.x;
    int lin = (b & 7) * 64 + (b >> 3);
    int n = lin >> 6, r = lin & 63;
    int oct = r >> 1, c0 = oct * 8, sh = r & 1;
    int tid = threadIdx.x;
    const float* ap = att + (size_t)n * K_ * S_ + sh * 8192 + tid * 4;
    const float* fp = fea + ((size_t)n * C_ + c0) * S_ + sh * 8192 + tid * 4;

    float acc[8][K_] = {};
    float4 av[K_], fv[8], na[K_], nf[8];
#pragma unroll
    for (int k = 0; k < K_; k++) av[k] = *(const float4*)(ap + (size_t)k * S_);
#pragma unroll
    for (int c = 0; c < 8; c++) fv[c] = *(const float4*)(fp + (size_t)c * S_);
#pragma unroll
    for (int it = 0; it < 8; it++) {
        int s = (it + 1) * 1024;
        if (it < 7) {
#pragma unroll
            for (int k = 0; k < K_; k++) na[k] = *(const float4*)(ap + (size_t)k * S_ + s);
#pragma unroll
            for (int c = 0; c < 8; c++) nf[c] = *(const float4*)(fp + (size_t)c * S_ + s);
        }
#pragma unroll
        for (int c = 0; c < 8; c++)
#pragma unroll
            for (int k = 0; k < K_; k++)
                acc[c][k] += fv[c].x*av[k].x + fv[c].y*av[k].y
                           + fv[c].z*av[k].z + fv[c].w*av[k].w;
        if (it < 7) {
#pragma unroll
            for (int k = 0; k < K_; k++) av[k] = na[k];
#pragma unroll
            for (int c = 0; c < 8; c++) fv[c] = nf[c];
        }
    }
    __shared__ float red[4][56];
    int lane = tid & 63, wv = tid >> 6;
#pragma unroll
    for (int i = 0; i < 56; i++) {
        float v = acc[i / K_][i % K_];
        for (int off = 32; off; off >>= 1) v += __shfl_xor(v, off, 64);
        if (lane == 0) red[wv][i] = v;
    }
    __syncthreads();
    if (tid < 56)
        pp[(((size_t)n * 2 + sh) * 32 + oct) * 64 + tid] =
            red[0][tid] + red[1][tid] + red[2][tid] + red[3][tid];
}

// ---------------- kernel B: reduce partials -> p_center -> wpt80, ebias, M2 ----
__global__ void k_center(const float* __restrict__ pp, const float* __restrict__ dp,
                         const float* __restrict__ Wq, const float* __restrict__ bq,
                         const float* __restrict__ Wk, const float* __restrict__ bk,
                         const float* __restrict__ Wp,
                         float* __restrict__ eb, float* __restrict__ m2,
                         float* __restrict__ wpt80) {
    int n = blockIdx.x, tid = threadIdx.x;
    __shared__ float pc[C_ * K_];     // [c][k]
    __shared__ float ql[HID_ * K_];   // [o][k]
    __shared__ float dinv[K_];
    if (tid < K_) {
        float d = 0.f;
        for (int t = 0; t < 32; t++) d += dp[((size_t)n * 32 + t) * 8 + tid];
        dinv[tid] = 1.f / d;
    }
    __syncthreads();
    for (int i = tid; i < C_ * K_; i += 256) {
        int c = i / K_, k = i - c * K_;
        int oct = c >> 3, ci = c & 7;
        float v = pp[(((size_t)n * 2 + 0) * 32 + oct) * 64 + ci * K_ + k]
                + pp[(((size_t)n * 2 + 1) * 32 + oct) * 64 + ci * K_ + k];
        pc[i] = v * dinv[k];
    }
    __syncthreads();
    if (tid < HID_ * K_) {
        int o = tid / K_, k = tid % K_;
        float s = bq[o];
        for (int c = 0; c < C_; c++) s += Wq[o * C_ + c] * pc[c * K_ + k];
        ql[tid] = s;
    }
    __syncthreads();
    // wpt80[c][80]: col 20w+j (j<17) = output o=17w+j; o<60 -> Wp1^T, 60..66 -> Wqk
    for (int i = tid; i < C_ * 80; i += 256) {
        int c = i / 80, cc = i % 80;
        int w = cc / 20, j = cc % 20;
        float v = 0.f;
        if (j < 17) {
            int o = 17 * w + j;
            if (o < 60) v = Wp[o * 2 * C_ + c];
            else if (o < 67) {
                int k = o - 60;
                for (int o2 = 0; o2 < HID_; o2++) v += ql[o2 * K_ + k] * Wk[o2 * C_ + c];
            }
        }
        wpt80[(size_t)n * C_ * 80 + i] = v;
    }
    if (tid < K_) {
        float s = 0.f;
        for (int o = 0; o < HID_; o++) s += ql[o * K_ + tid] * bk[o];
        eb[n * K_ + tid] = s;
    }
    for (int i = tid; i < OUTC_ * K_; i += 256) {
        int o = i / K_, k = i % K_;
        float s = 0.f;
        for (int c = 0; c < C_; c++) s += Wp[o * 2 * C_ + C_ + c] * pc[c * K_ + k];
        m2[(size_t)n * OUTC_ * K_ + i] = s;
    }
}

// ---------------- kernel C: fused energy/softmax/projection ----------------
// 512 blocks xcd-chunked; wave w owns outputs 17w..17w+16; thread owns 4 px
// LDS weights register-double-buffered: ds_reads for c+1 issued before c's FMAs
__global__ void __launch_bounds__(256, 2) k_main(
        const float* __restrict__ fea, const float* __restrict__ wpt80,
        const float* __restrict__ ebias, const float* __restrict__ m2,
        float* __restrict__ y, float* __restrict__ part) {
    int g = blockIdx.x;
    int lin = (g & 7) * 64 + (g >> 3);
    int n = lin >> 6, tile = lin & 63;
    int tid = threadIdx.x, lane = tid & 63, wv = tid >> 6;

    __shared__ __align__(16) float sw[2][5120];      // 2 x 20KB weight chunks
    __shared__ __align__(16) float sm2[424];
    __shared__ __align__(16) float a_lds[K_][256];
    __shared__ float tot[120];

    for (int i = tid; i < OUTC_ * K_; i += 256)
        sm2[i] = m2[(size_t)n * OUTC_ * K_ + i];

    const float* wsrc = wpt80 + (size_t)n * (C_ * 80);
    const float* fp = fea + (size_t)n * C_ * S_ + tile * 256 + lane * 4;

    float4 acc[17];
#pragma unroll
    for (int i = 0; i < 17; i++) acc[i] = make_float4(0.f, 0.f, 0.f, 0.f);

    {   // stage chunk 0
#pragma unroll
        for (int i = 0; i < 5; i++) {
            int fi = i * 1024 + wv * 256;            // wave-uniform lds base
            GLDS(wsrc + fi + lane * 4, &sw[0][fi]);
        }
    }
    // 8-deep fea channel prefetch (issued AFTER the GLDS -> counted waits work)
    float4 fbuf[8];
#pragma unroll
    for (int j = 0; j < 8; j++) fbuf[j] = *(const float4*)(fp + (size_t)j * S_);

    // GLDS are the 5 oldest outstanding; keep the 8 newest (fbuf) in flight
    asm volatile("s_waitcnt vmcnt(8) lgkmcnt(0)" ::: "memory");
    __builtin_amdgcn_s_barrier();

    const int wb = 20 * wv;
    for (int ch = 0; ch < 4; ch++) {
        int bb = ch & 1;
        if (ch < 3) {
            const float* s1 = wsrc + (ch + 1) * 5120;
#pragma unroll
            for (int i = 0; i < 5; i++) {
                int fi = i * 1024 + wv * 256;
                GLDS(s1 + fi + lane * 4, &sw[bb ^ 1][fi]);
            }
        }
        // preload weights for cc=0 of this chunk
        const float* w0p = &sw[bb][wb];
        float4 W0 = *(const float4*)w0p;
        float4 W1 = *(const float4*)(w0p + 4);
        float4 W2 = *(const float4*)(w0p + 8);
        float4 W3 = *(const float4*)(w0p + 12);
        float  WX = w0p[16];
#pragma unroll 8
        for (int cc = 0; cc < 64; cc++) {
            int cg = ch * 64 + cc;
            // issue NEXT channel's weight ds_reads now; lgkm wait lands after FMAs
            const float* wn = &sw[bb][((cc + 1) & 63) * 80 + wb];
            float4 n0 = *(const float4*)wn;
            float4 n1 = *(const float4*)(wn + 4);
            float4 n2 = *(const float4*)(wn + 8);
            float4 n3 = *(const float4*)(wn + 12);
            float  nX = wn[16];
            float4 f = fbuf[cg & 7];
            fbuf[cg & 7] = *(const float4*)(fp + (size_t)((cg + 8) & 255) * S_);
#define FMA4(j, ww) acc[j].x += (ww) * f.x; acc[j].y += (ww) * f.y; \
                    acc[j].z += (ww) * f.z; acc[j].w += (ww) * f.w;
            FMA4(0, W0.x) FMA4(1, W0.y) FMA4(2, W0.z) FMA4(3, W0.w)
            FMA4(4, W1.x) FMA4(5, W1.y) FMA4(6, W1.z) FMA4(7, W1.w)
            FMA4(8, W2.x) FMA4(9, W2.y) FMA4(10, W2.z) FMA4(11, W2.w)
            FMA4(12, W3.x) FMA4(13, W3.y) FMA4(14, W3.z) FMA4(15, W3.w)
            FMA4(16, WX)
#undef FMA4
            W0 = n0; W1 = n1; W2 = n2; W3 = n3; WX = nX;
        }
        // counted wait: next chunk's 5 GLDS done; 8 newest fea prefetches in flight
        asm volatile("s_waitcnt vmcnt(8)" ::: "memory");
        __builtin_amdgcn_s_barrier();
    }

    // wave 3 holds energies (outputs 60..66 = acc[9..15]); softmax over k per px
    if (wv == 3) {
        float4 a[K_];
#pragma unroll
        for (int k = 0; k < K_; k++) {
            float e = ebias[n * K_ + k];
            a[k] = make_float4(acc[9+k].x + e, acc[9+k].y + e,
                               acc[9+k].z + e, acc[9+k].w + e);
        }
        float4 mm = a[0];
#pragma unroll
        for (int k = 1; k < K_; k++) mm = f4max(mm, a[k]);
        float4 sum = make_float4(0.f, 0.f, 0.f, 0.f);
#pragma unroll
        for (int k = 0; k < K_; k++) {
            a[k] = make_float4(__expf(a[k].x - mm.x), __expf(a[k].y - mm.y),
                               __expf(a[k].z - mm.z), __expf(a[k].w - mm.w));
            sum.x += a[k].x; sum.y += a[k].y; sum.z += a[k].z; sum.w += a[k].w;
        }
        float4 inv = make_float4(1.f/sum.x, 1.f/sum.y, 1.f/sum.z, 1.f/sum.w);
#pragma unroll
        for (int k = 0; k < K_; k++)
            ((float4*)&a_lds[k][0])[lane] =
                make_float4(a[k].x*inv.x, a[k].y*inv.y, a[k].z*inv.z, a[k].w*inv.w);
    }
    __syncthreads();

    float4 a4[K_];
#pragma unroll
    for (int k = 0; k < K_; k++) a4[k] = ((const float4*)&a_lds[k][0])[lane];
    int nout = (wv == 3) ? 9 : 17;
    int ob = wv * 17;
#pragma unroll
    for (int i = 0; i < 17; i++) {
        if (i < nout) {
            int o = ob + i;
            float4 s = make_float4(0.f, 0.f, 0.f, 0.f);
#pragma unroll
            for (int k = 0; k < K_; k++) {
                float mv = sm2[o * K_ + k];
                s.x += mv * a4[k].x; s.y += mv * a4[k].y;
                s.z += mv * a4[k].z; s.w += mv * a4[k].w;
            }
            acc[i].x += s.x; acc[i].y += s.y; acc[i].z += s.z; acc[i].w += s.w;
        }
    }

    // store pre-BN y + per-block BN partials
    float* yp = y + (size_t)n * OUTC_ * S_ + tile * 256 + lane * 4;
#pragma unroll
    for (int i = 0; i < 17; i++) {
        if (i < nout) {
            int o = ob + i;
            *(float4*)(yp + (size_t)o * S_) = acc[i];
            float sm = acc[i].x + acc[i].y + acc[i].z + acc[i].w;
            float sq = acc[i].x*acc[i].x + acc[i].y*acc[i].y +
                       acc[i].z*acc[i].z + acc[i].w*acc[i].w;
            for (int off = 32; off; off >>= 1) {
                sm += __shfl_xor(sm, off, 64);
                sq += __shfl_xor(sq, off, 64);
            }
            if (lane == 0) { tot[o] = sm; tot[60 + o] = sq; }
        }
    }
    __syncthreads();
    if (tid < 120) part[(size_t)blockIdx.x * 120 + tid] = tot[tid];
}

// ---------------- kernel D: BN statistics ----------------
__global__ void k_bn(const float* __restrict__ part, const float* __restrict__ gamma,
                     const float* __restrict__ beta, float* __restrict__ scl,
                     float* __restrict__ shf) {
    int t = threadIdx.x & 127, q = threadIdx.x >> 7;   // 512 threads
    __shared__ float red[4][120];
    __shared__ float tot[120];
    if (t < 120) {
        float s = 0.f;
        for (int b = q * 128; b < q * 128 + 128; b++) s += part[(size_t)b * 120 + t];
        red[q][t] = s;
    }
    __syncthreads();
    if (threadIdx.x < 120)
        tot[threadIdx.x] = red[0][threadIdx.x] + red[1][threadIdx.x] +
                           red[2][threadIdx.x] + red[3][threadIdx.x];
    __syncthreads();
    if (threadIdx.x < OUTC_) {
        const float invn = 1.f / (float)(N_ * S_);
        float mean = tot[threadIdx.x] * invn;
        float var = tot[60 + threadIdx.x] * invn - mean * mean;
        float sc = gamma[threadIdx.x] * rsqrtf(var + BN_EPS);
        scl[threadIdx.x] = sc;
        shf[threadIdx.x] = beta[threadIdx.x] - mean * sc;
    }
}

// ---------------- kernel E: in-place BN apply + ReLU ----------------
__global__ void k_apply(float* __restrict__ y, const float* __restrict__ scl,
                        const float* __restrict__ shf) {
    int idx = blockIdx.x * 256 + threadIdx.x;          // float4 index
    int o = (idx >> 12) % OUTC_;
    float4 v = ((const float4*)y)[idx];
    float a = scl[o], b = shf[o];
    v.x = fmaxf(v.x * a + b, 0.f);
    v.y = fmaxf(v.y * a + b, 0.f);
    v.z = fmaxf(v.z * a + b, 0.f);
    v.w = fmaxf(v.w * a + b, 0.f);
    ((float4*)y)[idx] = v;
}

extern "C" void kernel_launch(void* const* d_in, const int* in_sizes, int n_in,
                              void* d_out, int out_size, void* d_ws, size_t ws_size,
                              hipStream_t stream) {
    const float* p_fea = (const float*)d_in[0];
    const float* p_seg = (const float*)d_in[1];
    const float* Wq    = (const float*)d_in[2];
    const float* bq    = (const float*)d_in[3];
    const float* Wk    = (const float*)d_in[4];
    const float* bk    = (const float*)d_in[5];
    const float* Wp    = (const float*)d_in[6];
    const float* gamma = (const float*)d_in[7];
    const float* beta  = (const float*)d_in[8];

    float* ws    = (float*)d_ws;
    float* pp    = ws + OFF_PP;
    float* dp    = ws + OFF_DP;
    float* eb    = ws + OFF_EB;
    float* m2    = ws + OFF_M2;
    float* wpt80 = ws + OFF_WPT80;
    float* att   = ws + OFF_ATT;
    float* part  = ws + OFF_PART;
    float* scl   = ws + OFF_SCL;
    float* shf   = ws + OFF_SHF;
    float* ybuf  = (float*)d_out;

    k_att<<<256, 256, 0, stream>>>(p_seg, att, dp);
    k_num<<<512, 256, 0, stream>>>(p_fea, att, pp);
    k_center<<<8, 256, 0, stream>>>(pp, dp, Wq, bq, Wk, bk, Wp, eb, m2, wpt80);
    k_main<<<512, 256, 0, stream>>>(p_fea, wpt80, eb, m2, ybuf, part);
    k_bn<<<1, 512, 0, stream>>>(part, gamma, beta, scl, shf);
    k_apply<<<(N_ * OUTC_ * S_ / 4) / 256, 256, 0, stream>>>(ybuf, scl, shf);
}

// Round 8
// 190.059 us; speedup vs baseline: 1.8690x; 1.8690x over previous
//
#include <hip/hip_runtime.h>

#define N_    8
#define C_    256
#define K_    7
#define HID_  10
#define OUTC_ 60
#define S_    16384
#define BN_EPS 1e-5f

// ---- workspace layout (float offsets, all 16B-aligned) ----
#define OFF_PP     0        // pool partials: [n][sh][oct][64] = 32768
#define OFF_DP     32768    // den partials:  [n*32+t][8] = 2048
#define OFF_EB     34816    // 64
#define OFF_M2     34880    // 3392
#define OFF_WPT96  38272    // N*256*96 = 196608 (col 24w+j = output 17w+j, j<17)
#define OFF_ATT    234880   // N*K*S = 917504
#define OFF_PART   1152384  // 1024*120 = 122880
#define OFF_SCL    1275264  // 64
#define OFF_SHF    1275328  // 64
// total 1275392 floats ~= 5.1 MB

#define GLDS(g, l) __builtin_amdgcn_global_load_lds( \
    (const __attribute__((address_space(1))) unsigned int*)(g), \
    (__attribute__((address_space(3))) unsigned int*)(l), 16, 0, 0)

__device__ __forceinline__ float4 f4max(float4 a, float4 b) {
    return make_float4(fmaxf(a.x,b.x), fmaxf(a.y,b.y), fmaxf(a.z,b.z), fmaxf(a.w,b.w));
}

// ---------------- kernel A0: class softmax (once per pixel) + den partials ----
__global__ void __launch_bounds__(256) k_att(
        const float* __restrict__ seg, float* __restrict__ att,
        float* __restrict__ dp) {
    int b = blockIdx.x;
    int lin = (b & 7) * 32 + (b >> 3);
    int n = lin >> 5, t = lin & 31;
    int tid = threadIdx.x;
    const float* sp = seg + (size_t)n * K_ * S_ + t * 512 + tid * 2;
    float* ap = att + (size_t)n * K_ * S_ + t * 512 + tid * 2;

    float2 e[K_];
    float mx = -1e30f, my = -1e30f;
#pragma unroll
    for (int k = 0; k < K_; k++) {
        e[k] = *(const float2*)(sp + (size_t)k * S_);
        mx = fmaxf(mx, e[k].x); my = fmaxf(my, e[k].y);
    }
    float sx = 0.f, sy = 0.f;
#pragma unroll
    for (int k = 0; k < K_; k++) {
        e[k].x = __expf(e[k].x - mx); sx += e[k].x;
        e[k].y = __expf(e[k].y - my); sy += e[k].y;
    }
    float ix = 1.f / sx, iy = 1.f / sy;
    float dsum[K_];
#pragma unroll
    for (int k = 0; k < K_; k++) {
        float2 a = make_float2(e[k].x * ix, e[k].y * iy);
        *(float2*)(ap + (size_t)k * S_) = a;
        dsum[k] = a.x + a.y;
    }
    __shared__ float red[4][K_];
    int lane = tid & 63, wv = tid >> 6;
#pragma unroll
    for (int k = 0; k < K_; k++) {
        float v = dsum[k];
        for (int off = 32; off; off >>= 1) v += __shfl_xor(v, off, 64);
        if (lane == 0) red[wv][k] = v;
    }
    __syncthreads();
    if (tid < K_)
        dp[((size_t)n * 32 + t) * 8 + tid] =
            red[0][tid] + red[1][tid] + red[2][tid] + red[3][tid];
}

// ---------------- kernel A1: pooling GEMM (round-6 proven form) ----------------
__global__ void __launch_bounds__(256) k_num(
        const float* __restrict__ fea, const float* __restrict__ att,
        float* __restrict__ pp) {
    int b = blockIdx.x;
    int lin = (b & 7) * 64 + (b >> 3);
    int n = lin >> 6, r = lin & 63;
    int oct = r >> 1, c0 = oct * 8, sh = r & 1;
    int tid = threadIdx.x;
    const float* ap = att + (size_t)n * K_ * S_ + sh * 8192 + tid * 4;
    const float* fp = fea + ((size_t)n * C_ + c0) * S_ + sh * 8192 + tid * 4;

    float acc[8][K_] = {};
#pragma unroll 2
    for (int it = 0; it < 8; it++) {
        int s = it * 1024;
        float4 av[K_], fv[8];
#pragma unroll
        for (int k = 0; k < K_; k++) av[k] = *(const float4*)(ap + (size_t)k * S_ + s);
#pragma unroll
        for (int c = 0; c < 8; c++) fv[c] = *(const float4*)(fp + (size_t)c * S_ + s);
#pragma unroll
        for (int c = 0; c < 8; c++)
#pragma unroll
            for (int k = 0; k < K_; k++)
                acc[c][k] += fv[c].x*av[k].x + fv[c].y*av[k].y
                           + fv[c].z*av[k].z + fv[c].w*av[k].w;
    }
    __shared__ float red[4][56];
    int lane = tid & 63, wv = tid >> 6;
#pragma unroll
    for (int i = 0; i < 56; i++) {
        float v = acc[i / K_][i % K_];
        for (int off = 32; off; off >>= 1) v += __shfl_xor(v, off, 64);
        if (lane == 0) red[wv][i] = v;
    }
    __syncthreads();
    if (tid < 56)
        pp[(((size_t)n * 2 + sh) * 32 + oct) * 64 + tid] =
            red[0][tid] + red[1][tid] + red[2][tid] + red[3][tid];
}

// ---------------- kernel B: reduce partials -> p_center -> wpt96, ebias, M2 ----
__global__ void k_center(const float* __restrict__ pp, const float* __restrict__ dp,
                         const float* __restrict__ Wq, const float* __restrict__ bq,
                         const float* __restrict__ Wk, const float* __restrict__ bk,
                         const float* __restrict__ Wp,
                         float* __restrict__ eb, float* __restrict__ m2,
                         float* __restrict__ wpt96) {
    int n = blockIdx.x, tid = threadIdx.x;
    __shared__ float pc[C_ * K_];     // [c][k]
    __shared__ float ql[HID_ * K_];   // [o][k]
    __shared__ float dinv[K_];
    if (tid < K_) {
        float d = 0.f;
        for (int t = 0; t < 32; t++) d += dp[((size_t)n * 32 + t) * 8 + tid];
        dinv[tid] = 1.f / d;
    }
    __syncthreads();
    for (int i = tid; i < C_ * K_; i += 256) {
        int c = i / K_, k = i - c * K_;
        int oct = c >> 3, ci = c & 7;
        float v = pp[(((size_t)n * 2 + 0) * 32 + oct) * 64 + ci * K_ + k]
                + pp[(((size_t)n * 2 + 1) * 32 + oct) * 64 + ci * K_ + k];
        pc[i] = v * dinv[k];
    }
    __syncthreads();
    if (tid < HID_ * K_) {
        int o = tid / K_, k = tid % K_;
        float s = bq[o];
        for (int c = 0; c < C_; c++) s += Wq[o * C_ + c] * pc[c * K_ + k];
        ql[tid] = s;
    }
    __syncthreads();
    // wpt96[c][96]: col 24w+j (j<17) = output o=17w+j; o<60 -> Wp1^T, 60..66 -> Wqk
    for (int i = tid; i < C_ * 96; i += 256) {
        int c = i / 96, cc = i % 96;
        int w = cc / 24, j = cc % 24;
        float v = 0.f;
        if (j < 17) {
            int o = 17 * w + j;
            if (o < 60) v = Wp[o * 2 * C_ + c];
            else if (o < 67) {
                int k = o - 60;
                for (int o2 = 0; o2 < HID_; o2++) v += ql[o2 * K_ + k] * Wk[o2 * C_ + c];
            }
        }
        wpt96[(size_t)n * C_ * 96 + i] = v;
    }
    if (tid < K_) {
        float s = 0.f;
        for (int o = 0; o < HID_; o++) s += ql[o * K_ + tid] * bk[o];
        eb[n * K_ + tid] = s;
    }
    for (int i = tid; i < OUTC_ * K_; i += 256) {
        int o = i / K_, k = i % K_;
        float s = 0.f;
        for (int c = 0; c < C_; c++) s += Wp[o * 2 * C_ + C_ + c] * pc[c * K_ + k];
        m2[(size_t)n * OUTC_ * K_ + i] = s;
    }
}

// ---------------- kernel C: fused energy/softmax/projection ----------------
// 1024 blocks xcd-chunked; 128 px/block (float2/thread); wave w owns outputs
// 17w..17w+16; 32-channel weight chunks (12KB) double-buffered in LDS.
__global__ void __launch_bounds__(256, 4) k_main(
        const float* __restrict__ fea, const float* __restrict__ wpt96,
        const float* __restrict__ ebias, const float* __restrict__ m2,
        float* __restrict__ y, float* __restrict__ part) {
    int g = blockIdx.x;
    int lin = (g & 7) * 128 + (g >> 3);
    int n = lin >> 7, tile = lin & 127;
    int tid = threadIdx.x, lane = tid & 63, wv = tid >> 6;

    __shared__ __align__(16) float sw[2][3072];      // 2 x 12KB (32ch x 96col)
    __shared__ __align__(16) float sm2[424];
    __shared__ __align__(16) float a_lds[K_][128];
    __shared__ float tot[120];

    for (int i = tid; i < OUTC_ * K_; i += 256)
        sm2[i] = m2[(size_t)n * OUTC_ * K_ + i];

    const float* wsrc = wpt96 + (size_t)n * (C_ * 96);
    const float* fp = fea + (size_t)n * C_ * S_ + tile * 128 + lane * 2;

    float2 acc[17];
#pragma unroll
    for (int i = 0; i < 17; i++) acc[i] = make_float2(0.f, 0.f);

    {   // stage chunk 0 (3 GLDS: 3072 floats = 3 x 4waves x 256)
#pragma unroll
        for (int i = 0; i < 3; i++) {
            int fi = i * 1024 + wv * 256;            // wave-uniform lds base
            GLDS(wsrc + fi + lane * 4, &sw[0][fi]);
        }
    }
    // 8-deep fea channel prefetch (issued AFTER the GLDS -> counted waits work)
    float2 fbuf[8];
#pragma unroll
    for (int j = 0; j < 8; j++) fbuf[j] = *(const float2*)(fp + (size_t)j * S_);

    // 3 GLDS are the oldest outstanding; keep the 8 newest (fbuf) in flight
    asm volatile("s_waitcnt vmcnt(8) lgkmcnt(0)" ::: "memory");
    __builtin_amdgcn_s_barrier();

    const int wb = 24 * wv;
    for (int ch = 0; ch < 8; ch++) {
        int bb = ch & 1;
        if (ch < 7) {
            const float* s1 = wsrc + (ch + 1) * 3072;
#pragma unroll
            for (int i = 0; i < 3; i++) {
                int fi = i * 1024 + wv * 256;
                GLDS(s1 + fi + lane * 4, &sw[bb ^ 1][fi]);
            }
        }
        // preload weights for cc=0 of this chunk
        const float* w0p = &sw[bb][wb];
        float4 W0 = *(const float4*)w0p;
        float4 W1 = *(const float4*)(w0p + 4);
        float4 W2 = *(const float4*)(w0p + 8);
        float4 W3 = *(const float4*)(w0p + 12);
        float  WX = w0p[16];
#pragma unroll 8
        for (int cc = 0; cc < 32; cc++) {
            int cg = ch * 32 + cc;
            // issue NEXT channel's weight ds_reads; lgkm wait lands after FMAs
            const float* wn = &sw[bb][((cc + 1) & 31) * 96 + wb];
            float4 n0 = *(const float4*)wn;
            float4 n1 = *(const float4*)(wn + 4);
            float4 n2 = *(const float4*)(wn + 8);
            float4 n3 = *(const float4*)(wn + 12);
            float  nX = wn[16];
            float2 f = fbuf[cg & 7];
            fbuf[cg & 7] = *(const float2*)(fp + (size_t)((cg + 8) & 255) * S_);
#define FMA2(j, ww) acc[j].x += (ww) * f.x; acc[j].y += (ww) * f.y;
            FMA2(0, W0.x) FMA2(1, W0.y) FMA2(2, W0.z) FMA2(3, W0.w)
            FMA2(4, W1.x) FMA2(5, W1.y) FMA2(6, W1.z) FMA2(7, W1.w)
            FMA2(8, W2.x) FMA2(9, W2.y) FMA2(10, W2.z) FMA2(11, W2.w)
            FMA2(12, W3.x) FMA2(13, W3.y) FMA2(14, W3.z) FMA2(15, W3.w)
            FMA2(16, WX)
#undef FMA2
            W0 = n0; W1 = n1; W2 = n2; W3 = n3; WX = nX;
        }
        // counted wait: next chunk's 3 GLDS done; 8 newest fea prefetches in flight
        asm volatile("s_waitcnt vmcnt(8)" ::: "memory");
        __builtin_amdgcn_s_barrier();
    }

    // wave 3 holds energies (outputs 60..66 = acc[9..15]); softmax over k per px
    if (wv == 3) {
        float2 a[K_];
#pragma unroll
        for (int k = 0; k < K_; k++) {
            float e = ebias[n * K_ + k];
            a[k] = make_float2(acc[9 + k].x + e, acc[9 + k].y + e);
        }
        float2 mm = a[0];
#pragma unroll
        for (int k = 1; k < K_; k++) {
            mm.x = fmaxf(mm.x, a[k].x); mm.y = fmaxf(mm.y, a[k].y);
        }
        float2 sum = make_float2(0.f, 0.f);
#pragma unroll
        for (int k = 0; k < K_; k++) {
            a[k] = make_float2(__expf(a[k].x - mm.x), __expf(a[k].y - mm.y));
            sum.x += a[k].x; sum.y += a[k].y;
        }
        float2 inv = make_float2(1.f / sum.x, 1.f / sum.y);
#pragma unroll
        for (int k = 0; k < K_; k++)
            ((float2*)&a_lds[k][0])[lane] = make_float2(a[k].x * inv.x, a[k].y * inv.y);
    }
    __syncthreads();

    float2 a2[K_];
#pragma unroll
    for (int k = 0; k < K_; k++) a2[k] = ((const float2*)&a_lds[k][0])[lane];
    int nout = (wv == 3) ? 9 : 17;
    int ob = wv * 17;
#pragma unroll
    for (int i = 0; i < 17; i++) {
        if (i < nout) {
            int o = ob + i;
            float2 s = make_float2(0.f, 0.f);
#pragma unroll
            for (int k = 0; k < K_; k++) {
                float mv = sm2[o * K_ + k];
                s.x += mv * a2[k].x; s.y += mv * a2[k].y;
            }
            acc[i].x += s.x; acc[i].y += s.y;
        }
    }

    // store pre-BN y + per-block BN partials
    float* yp = y + (size_t)n * OUTC_ * S_ + tile * 128 + lane * 2;
#pragma unroll
    for (int i = 0; i < 17; i++) {
        if (i < nout) {
            int o = ob + i;
            *(float2*)(yp + (size_t)o * S_) = acc[i];
            float sm = acc[i].x + acc[i].y;
            float sq = acc[i].x * acc[i].x + acc[i].y * acc[i].y;
            for (int off = 32; off; off >>= 1) {
                sm += __shfl_xor(sm, off, 64);
                sq += __shfl_xor(sq, off, 64);
            }
            if (lane == 0) { tot[o] = sm; tot[60 + o] = sq; }
        }
    }
    __syncthreads();
    if (tid < 120) part[(size_t)blockIdx.x * 120 + tid] = tot[tid];
}

// ---------------- kernel D: BN statistics ----------------
__global__ void k_bn(const float* __restrict__ part, const float* __restrict__ gamma,
                     const float* __restrict__ beta, float* __restrict__ scl,
                     float* __restrict__ shf) {
    int t = threadIdx.x & 127, q = threadIdx.x >> 7;   // 512 threads
    __shared__ float red[4][120];
    __shared__ float tot[120];
    if (t < 120) {
        float s = 0.f;
        for (int b = q * 256; b < q * 256 + 256; b++) s += part[(size_t)b * 120 + t];
        red[q][t] = s;
    }
    __syncthreads();
    if (threadIdx.x < 120)
        tot[threadIdx.x] = red[0][threadIdx.x] + red[1][threadIdx.x] +
                           red[2][threadIdx.x] + red[3][threadIdx.x];
    __syncthreads();
    if (threadIdx.x < OUTC_) {
        const float invn = 1.f / (float)(N_ * S_);
        float mean = tot[threadIdx.x] * invn;
        float var = tot[60 + threadIdx.x] * invn - mean * mean;
        float sc = gamma[threadIdx.x] * rsqrtf(var + BN_EPS);
        scl[threadIdx.x] = sc;
        shf[threadIdx.x] = beta[threadIdx.x] - mean * sc;
    }
}

// ---------------- kernel E: in-place BN apply + ReLU ----------------
__global__ void k_apply(float* __restrict__ y, const float* __restrict__ scl,
                        const float* __restrict__ shf) {
    int idx = blockIdx.x * 256 + threadIdx.x;          // float4 index
    int o = (idx >> 12) % OUTC_;
    float4 v = ((const float4*)y)[idx];
    float a = scl[o], b = shf[o];
    v.x = fmaxf(v.x * a + b, 0.f);
    v.y = fmaxf(v.y * a + b, 0.f);
    v.z = fmaxf(v.z * a + b, 0.f);
    v.w = fmaxf(v.w * a + b, 0.f);
    ((float4*)y)[idx] = v;
}

extern "C" void kernel_launch(void* const* d_in, const int* in_sizes, int n_in,
                              void* d_out, int out_size, void* d_ws, size_t ws_size,
                              hipStream_t stream) {
    const float* p_fea = (const float*)d_in[0];
    const float* p_seg = (const float*)d_in[1];
    const float* Wq    = (const float*)d_in[2];
    const float* bq    = (const float*)d_in[3];
    const float* Wk    = (const float*)d_in[4];
    const float* bk    = (const float*)d_in[5];
    const float* Wp    = (const float*)d_in[6];
    const float* gamma = (const float*)d_in[7];
    const float* beta  = (const float*)d_in[8];

    float* ws    = (float*)d_ws;
    float* pp    = ws + OFF_PP;
    float* dp    = ws + OFF_DP;
    float* eb    = ws + OFF_EB;
    float* m2    = ws + OFF_M2;
    float* wpt96 = ws + OFF_WPT96;
    float* att   = ws + OFF_ATT;
    float* part  = ws + OFF_PART;
    float* scl   = ws + OFF_SCL;
    float* shf   = ws + OFF_SHF;
    float* ybuf  = (float*)d_out;

    k_att<<<256, 256, 0, stream>>>(p_seg, att, dp);
    k_num<<<512, 256, 0, stream>>>(p_fea, att, pp);
    k_center<<<8, 256, 0, stream>>>(pp, dp, Wq, bq, Wk, bk, Wp, eb, m2, wpt96);
    k_main<<<1024, 256, 0, stream>>>(p_fea, wpt96, eb, m2, ybuf, part);
    k_bn<<<1, 512, 0, stream>>>(part, gamma, beta, scl, shf);
    k_apply<<<(N_ * OUTC_ * S_ / 4) / 256, 256, 0, stream>>>(ybuf, scl, shf);
}

// Round 9
// 156.948 us; speedup vs baseline: 2.2633x; 1.2110x over previous
//
#include <hip/hip_runtime.h>
#include <hip/hip_bf16.h>

#define N_    8
#define C_    256
#define K_    7
#define HID_  10
#define OUTC_ 60
#define S_    16384
#define BN_EPS 1e-5f

// ---- workspace layout (float offsets, all 16B-aligned) ----
#define OFF_PP     0        // pool partials: [n][qt4][oct32][64] = 65536
#define OFF_DP     65536    // den partials:  [n*32+t][8] = 2048
#define OFF_EB     67584    // 64
#define OFF_WB16   67648    // bf16 weight frag images: 8n x 4ch x 6144 ush = 98304 fl
#define OFF_M2B    165952   // bf16 M2 images: 8n x 640 ush = 2560 fl
#define OFF_ATT    168512   // N*K*S = 917504
#define OFF_PART   1086016  // 1024*120 = 122880
#define OFF_SCL    1208896  // 64
#define OFF_SHF    1208960  // 64
// total 1209024 floats ~= 4.84 MB

#define GLDS(g, l) __builtin_amdgcn_global_load_lds( \
    (const __attribute__((address_space(1))) unsigned int*)(g), \
    (__attribute__((address_space(3))) unsigned int*)(l), 16, 0, 0)

typedef __attribute__((ext_vector_type(8))) short bfrag;   // 8 bf16 = 4 VGPR
typedef __attribute__((ext_vector_type(4))) float f32x4;   // MFMA acc

static __device__ __forceinline__ unsigned short f2bf(float f) {
    __hip_bfloat16 h = __float2bfloat16(f);
    return *reinterpret_cast<unsigned short*>(&h);
}

// ---------------- kernel A0: class softmax (once per pixel) + den partials ----
__global__ void __launch_bounds__(256) k_att(
        const float* __restrict__ seg, float* __restrict__ att,
        float* __restrict__ dp) {
    int b = blockIdx.x;
    int lin = (b & 7) * 32 + (b >> 3);
    int n = lin >> 5, t = lin & 31;
    int tid = threadIdx.x;
    const float* sp = seg + (size_t)n * K_ * S_ + t * 512 + tid * 2;
    float* ap = att + (size_t)n * K_ * S_ + t * 512 + tid * 2;

    float2 e[K_];
    float mx = -1e30f, my = -1e30f;
#pragma unroll
    for (int k = 0; k < K_; k++) {
        e[k] = *(const float2*)(sp + (size_t)k * S_);
        mx = fmaxf(mx, e[k].x); my = fmaxf(my, e[k].y);
    }
    float sx = 0.f, sy = 0.f;
#pragma unroll
    for (int k = 0; k < K_; k++) {
        e[k].x = __expf(e[k].x - mx); sx += e[k].x;
        e[k].y = __expf(e[k].y - my); sy += e[k].y;
    }
    float ix = 1.f / sx, iy = 1.f / sy;
    float dsum[K_];
#pragma unroll
    for (int k = 0; k < K_; k++) {
        float2 a = make_float2(e[k].x * ix, e[k].y * iy);
        *(float2*)(ap + (size_t)k * S_) = a;
        dsum[k] = a.x + a.y;
    }
    __shared__ float red[4][K_];
    int lane = tid & 63, wv = tid >> 6;
#pragma unroll
    for (int k = 0; k < K_; k++) {
        float v = dsum[k];
        for (int off = 32; off; off >>= 1) v += __shfl_xor(v, off, 64);
        if (lane == 0) red[wv][k] = v;
    }
    __syncthreads();
    if (tid < K_)
        dp[((size_t)n * 32 + t) * 8 + tid] =
            red[0][tid] + red[1][tid] + red[2][tid] + red[3][tid];
}

// ---------------- kernel A1: pooling GEMM (1024 blocks for TLP) ----------------
__global__ void __launch_bounds__(256) k_num(
        const float* __restrict__ fea, const float* __restrict__ att,
        float* __restrict__ pp) {
    int b = blockIdx.x;
    int lin = (b & 7) * 128 + (b >> 3);
    int n = lin >> 7, rr = lin & 127;
    int oct = rr >> 2, qt = rr & 3, c0 = oct * 8;
    int tid = threadIdx.x;
    const float* ap = att + (size_t)n * K_ * S_ + qt * 4096 + tid * 4;
    const float* fp = fea + ((size_t)n * C_ + c0) * S_ + qt * 4096 + tid * 4;

    float acc[8][K_] = {};
#pragma unroll 2
    for (int it = 0; it < 4; it++) {
        int s = it * 1024;
        float4 av[K_], fv[8];
#pragma unroll
        for (int k = 0; k < K_; k++) av[k] = *(const float4*)(ap + (size_t)k * S_ + s);
#pragma unroll
        for (int c = 0; c < 8; c++) fv[c] = *(const float4*)(fp + (size_t)c * S_ + s);
#pragma unroll
        for (int c = 0; c < 8; c++)
#pragma unroll
            for (int k = 0; k < K_; k++)
                acc[c][k] += fv[c].x*av[k].x + fv[c].y*av[k].y
                           + fv[c].z*av[k].z + fv[c].w*av[k].w;
    }
    __shared__ float red[4][56];
    int lane = tid & 63, wv = tid >> 6;
#pragma unroll
    for (int i = 0; i < 56; i++) {
        float v = acc[i / K_][i % K_];
        for (int off = 32; off; off >>= 1) v += __shfl_xor(v, off, 64);
        if (lane == 0) red[wv][i] = v;
    }
    __syncthreads();
    if (tid < 56)
        pp[(((size_t)n * 4 + qt) * 32 + oct) * 64 + tid] =
            red[0][tid] + red[1][tid] + red[2][tid] + red[3][tid];
}

// ---- kernel B: reduce partials -> p_center -> bf16 weight/M2 frag images ----
__global__ void k_center(const float* __restrict__ pp, const float* __restrict__ dp,
                         const float* __restrict__ Wq, const float* __restrict__ bq,
                         const float* __restrict__ Wk, const float* __restrict__ bk,
                         const float* __restrict__ Wp,
                         float* __restrict__ eb, float* __restrict__ m2b,
                         float* __restrict__ wb16) {
    int n = blockIdx.x, tid = threadIdx.x;
    __shared__ float pc[C_ * K_];     // [c][k]
    __shared__ float ql[HID_ * K_];   // [o][k]
    __shared__ float dinv[K_];
    if (tid < K_) {
        float d = 0.f;
        for (int t = 0; t < 32; t++) d += dp[((size_t)n * 32 + t) * 8 + tid];
        dinv[tid] = 1.f / d;
    }
    __syncthreads();
    for (int i = tid; i < C_ * K_; i += 256) {
        int c = i / K_, k = i - c * K_;
        int oct = c >> 3, ci = c & 7;
        float v = 0.f;
#pragma unroll
        for (int qt = 0; qt < 4; qt++)
            v += pp[(((size_t)n * 4 + qt) * 32 + oct) * 64 + ci * K_ + k];
        pc[i] = v * dinv[k];
    }
    __syncthreads();
    if (tid < HID_ * K_) {
        int o = tid / K_, k = tid % K_;
        float s = bq[o];
        for (int c = 0; c < C_; c++) s += Wq[o * C_ + c] * pc[c * K_ + k];
        ql[tid] = s;
    }
    __syncthreads();
    // bf16 weight image: [4 chunks][6144]: row o (0..79, pad>=80 zero), col j (0..71,
    // j>=64 zero); c = ch*64+j. o<60: Wp1^T; 60..66: Wqk (query folded into Wk); else 0.
    unsigned short* wp16 = (unsigned short*)wb16 + (size_t)n * 24576;
    for (int i = tid; i < 24576; i += 256) {
        int ch = i / 6144, r = i - ch * 6144;
        int o = r / 72, j = r - o * 72;
        float v = 0.f;
        if (o < 80 && j < 64) {
            int c = ch * 64 + j;
            if (o < 60) v = Wp[o * 2 * C_ + c];
            else if (o < 67) {
                int k = o - 60;
                for (int o2 = 0; o2 < HID_; o2++) v += ql[o2 * K_ + k] * Wk[o2 * C_ + c];
            }
        }
        wp16[i] = f2bf(v);
    }
    // bf16 M2 image: [80][8]: M2[o][k] = Wp2 @ p_center, k=7 col zero
    unsigned short* mp16 = (unsigned short*)m2b + (size_t)n * 640;
    for (int i = tid; i < 640; i += 256) {
        int o = i >> 3, k = i & 7;
        float v = 0.f;
        if (k < 7 && o < 60) {
            for (int c = 0; c < C_; c++) v += Wp[o * 2 * C_ + C_ + c] * pc[c * K_ + k];
        }
        mp16[i] = f2bf(v);
    }
    if (tid < K_) {
        float s = 0.f;
        for (int o = 0; o < HID_; o++) s += ql[o * K_ + tid] * bk[o];
        eb[n * K_ + tid] = s;
    }
}

// ---------------- kernel C: MFMA fused energy/softmax/projection ----------------
// 1024 blocks xcd-chunked; 128 px/block; 4 waves, wave w owns px rows 32w..32w+31.
// D[16px][16out] = mfma_16x16x32_bf16(feaT frag, weight frag); K = 256 ch in 4 chunks.
__global__ void __launch_bounds__(256) k_main(
        const float* __restrict__ fea, const float* __restrict__ wb16,
        const float* __restrict__ ebias, const float* __restrict__ m2b,
        float* __restrict__ y, float* __restrict__ part) {
    int g = blockIdx.x;
    int lin = (g & 7) * 128 + (g >> 3);
    int n = lin >> 7, tile = lin & 127;
    int tid = threadIdx.x, lane = tid & 63, wv = tid >> 6;
    int r15 = lane & 15, kg = (lane >> 4) << 3, pg = (lane >> 4) << 2;

    __shared__ unsigned short wlds[2][6144];   // weight chunk images (24 KB)
    __shared__ unsigned short feaT[2][9216];   // [128 px][72 c] bf16 (36 KB)
    __shared__ unsigned short abf[128 * 8];    // attention [px][8k] bf16
    __shared__ unsigned short m2l[640];        // M2 [80][8] bf16
    __shared__ float att_e[K_][128];
    __shared__ float ebl[8];
    __shared__ float redm[4][80];
    __shared__ float redq[4][80];

    const unsigned int* wsrc = (const unsigned int*)wb16 + (size_t)n * 12288;
    const unsigned int* m2s  = (const unsigned int*)m2b + (size_t)n * 320;
    for (int i = tid; i < 320; i += 256) ((unsigned int*)m2l)[i] = m2s[i];
    if (tid < K_) ebl[tid] = ebias[n * K_ + tid];

    const float* fbase = fea + (size_t)n * C_ * S_ + tile * 128;
    int cr2 = tid >> 3, h = tid & 7;           // c-pair + px-octant for staging

    f32x4 acc[5][2];
#pragma unroll
    for (int ot = 0; ot < 5; ot++) { acc[ot][0] = (f32x4)0.f; acc[ot][1] = (f32x4)0.f; }

    // prologue: stage weights chunk 0 (GLDS) + fea chunk 0 (reg -> bf16 transpose)
#pragma unroll
    for (int rnd = 0; rnd < 3; rnd++)
        GLDS(wsrc + rnd * 1024 + wv * 256 + lane * 4,
             &((unsigned int*)wlds[0])[rnd * 1024 + wv * 256]);
    {
        const float* bp = fbase + (size_t)(cr2 * 2) * S_ + h * 16;
        float4 v0[4], v1[4];
#pragma unroll
        for (int i = 0; i < 4; i++) v0[i] = *(const float4*)(bp + i * 4);
#pragma unroll
        for (int i = 0; i < 4; i++) v1[i] = *(const float4*)(bp + S_ + i * 4);
        unsigned int* dst = (unsigned int*)feaT[0];
#pragma unroll
        for (int i = 0; i < 4; i++)
#pragma unroll
            for (int e = 0; e < 4; e++) {
                int px = h * 16 + i * 4 + e;
                dst[px * 36 + cr2] = (unsigned int)f2bf(((const float*)&v0[i])[e])
                                   | ((unsigned int)f2bf(((const float*)&v1[i])[e]) << 16);
            }
    }
    asm volatile("s_waitcnt vmcnt(0) lgkmcnt(0)" ::: "memory");
    __builtin_amdgcn_s_barrier();

#pragma unroll
    for (int ch = 0; ch < 4; ch++) {
        int bb = ch & 1;
        float4 s0[4], s1[4];
        if (ch < 3) {
#pragma unroll
            for (int rnd = 0; rnd < 3; rnd++)
                GLDS(wsrc + (ch + 1) * 3072 + rnd * 1024 + wv * 256 + lane * 4,
                     &((unsigned int*)wlds[bb ^ 1])[rnd * 1024 + wv * 256]);
            const float* bp = fbase + (size_t)((ch + 1) * 64 + cr2 * 2) * S_ + h * 16;
#pragma unroll
            for (int i = 0; i < 4; i++) s0[i] = *(const float4*)(bp + i * 4);
#pragma unroll
            for (int i = 0; i < 4; i++) s1[i] = *(const float4*)(bp + S_ + i * 4);
        }
        // MFMA on current chunk: 2 K-steps x 5 out-tiles x 2 px-tiles
        const unsigned short* fb = feaT[bb];
        const unsigned short* wb = wlds[bb];
#pragma unroll
        for (int ks = 0; ks < 2; ks++) {
            bfrag a0 = *(const bfrag*)&fb[(wv * 32 + r15) * 72 + ks * 32 + kg];
            bfrag a1 = *(const bfrag*)&fb[(wv * 32 + 16 + r15) * 72 + ks * 32 + kg];
#pragma unroll
            for (int ot = 0; ot < 5; ot++) {
                bfrag b = *(const bfrag*)&wb[(ot * 16 + r15) * 72 + ks * 32 + kg];
                acc[ot][0] = __builtin_amdgcn_mfma_f32_16x16x32_bf16(a0, b, acc[ot][0], 0, 0, 0);
                acc[ot][1] = __builtin_amdgcn_mfma_f32_16x16x32_bf16(a1, b, acc[ot][1], 0, 0, 0);
            }
        }
        if (ch < 3) {   // transpose-write next fea chunk (vmcnt wait lands here)
            unsigned int* dst = (unsigned int*)feaT[bb ^ 1];
#pragma unroll
            for (int i = 0; i < 4; i++)
#pragma unroll
                for (int e = 0; e < 4; e++) {
                    int px = h * 16 + i * 4 + e;
                    dst[px * 36 + cr2] = (unsigned int)f2bf(((const float*)&s0[i])[e])
                                       | ((unsigned int)f2bf(((const float*)&s1[i])[e]) << 16);
                }
        }
        asm volatile("s_waitcnt vmcnt(0) lgkmcnt(0)" ::: "memory");
        __builtin_amdgcn_s_barrier();
    }

    // energies: cols 60..63 in out-tile 3 (local 12..15), 64..66 in tile 4 (local 0..2)
    if (r15 >= 12) {
        int k = r15 - 12;
#pragma unroll
        for (int pxt = 0; pxt < 2; pxt++)
#pragma unroll
            for (int r = 0; r < 4; r++)
                att_e[k][wv * 32 + pxt * 16 + pg + r] = acc[3][pxt][r];
    }
    if (r15 < 3) {
        int k = 4 + r15;
#pragma unroll
        for (int pxt = 0; pxt < 2; pxt++)
#pragma unroll
            for (int r = 0; r < 4; r++)
                att_e[k][wv * 32 + pxt * 16 + pg + r] = acc[4][pxt][r];
    }
    __syncthreads();
    if (tid < 128) {   // per-px class softmax -> bf16 attention fragments
        float e[K_], mx = -1e30f;
#pragma unroll
        for (int k = 0; k < K_; k++) { e[k] = att_e[k][tid] + ebl[k]; mx = fmaxf(mx, e[k]); }
        float sum = 0.f;
#pragma unroll
        for (int k = 0; k < K_; k++) { e[k] = __expf(e[k] - mx); sum += e[k]; }
        float inv = 1.f / sum;
        unsigned int* ab = (unsigned int*)abf;
        ab[tid * 4 + 0] = (unsigned int)f2bf(e[0] * inv) | ((unsigned int)f2bf(e[1] * inv) << 16);
        ab[tid * 4 + 1] = (unsigned int)f2bf(e[2] * inv) | ((unsigned int)f2bf(e[3] * inv) << 16);
        ab[tid * 4 + 2] = (unsigned int)f2bf(e[4] * inv) | ((unsigned int)f2bf(e[5] * inv) << 16);
        ab[tid * 4 + 3] = (unsigned int)f2bf(e[6] * inv);
    }
    __syncthreads();

    // y += M2 @ attention  (one K=32 MFMA, k>=8 lanes contribute zero)
    bfrag az = (bfrag)(short)0;
    bfrag a20 = az, a21 = az;
    if (lane < 16) {
        a20 = *(const bfrag*)&abf[(wv * 32 + r15) * 8];
        a21 = *(const bfrag*)&abf[(wv * 32 + 16 + r15) * 8];
    }
#pragma unroll
    for (int ot = 0; ot < 5; ot++) {
        bfrag b2 = az;
        if (lane < 16) b2 = *(const bfrag*)&m2l[(ot * 16 + r15) * 8];
        acc[ot][0] = __builtin_amdgcn_mfma_f32_16x16x32_bf16(a20, b2, acc[ot][0], 0, 0, 0);
        acc[ot][1] = __builtin_amdgcn_mfma_f32_16x16x32_bf16(a21, b2, acc[ot][1], 0, 0, 0);
    }

    // store pre-BN y (cols < 60) + per-block BN partials
    float* ybase = y + (size_t)n * OUTC_ * S_ + tile * 128 + wv * 32 + pg;
#pragma unroll
    for (int ot = 0; ot < 5; ot++) {
        int o = ot * 16 + r15;
        float sm_ = 0.f, sq_ = 0.f;
#pragma unroll
        for (int pxt = 0; pxt < 2; pxt++) {
            f32x4 v = acc[ot][pxt];
            if (o < OUTC_)
                *(f32x4*)(ybase + (size_t)o * S_ + pxt * 16) = v;
            sm_ += v[0] + v[1] + v[2] + v[3];
            sq_ += v[0]*v[0] + v[1]*v[1] + v[2]*v[2] + v[3]*v[3];
        }
        sm_ += __shfl_xor(sm_, 16, 64); sm_ += __shfl_xor(sm_, 32, 64);
        sq_ += __shfl_xor(sq_, 16, 64); sq_ += __shfl_xor(sq_, 32, 64);
        if (lane < 16) { redm[wv][ot * 16 + lane] = sm_; redq[wv][ot * 16 + lane] = sq_; }
    }
    __syncthreads();
    if (tid < 120) {
        float s;
        if (tid < OUTC_)
            s = redm[0][tid] + redm[1][tid] + redm[2][tid] + redm[3][tid];
        else {
            int o = tid - OUTC_;
            s = redq[0][o] + redq[1][o] + redq[2][o] + redq[3][o];
        }
        part[(size_t)g * 120 + tid] = s;
    }
}

// ---------------- kernel D: BN statistics ----------------
__global__ void k_bn(const float* __restrict__ part, const float* __restrict__ gamma,
                     const float* __restrict__ beta, float* __restrict__ scl,
                     float* __restrict__ shf) {
    int t = threadIdx.x & 127, q = threadIdx.x >> 7;   // 512 threads
    __shared__ float red[4][120];
    __shared__ float tot[120];
    if (t < 120) {
        float s = 0.f;
        for (int b = q * 256; b < q * 256 + 256; b++) s += part[(size_t)b * 120 + t];
        red[q][t] = s;
    }
    __syncthreads();
    if (threadIdx.x < 120)
        tot[threadIdx.x] = red[0][threadIdx.x] + red[1][threadIdx.x] +
                           red[2][threadIdx.x] + red[3][threadIdx.x];
    __syncthreads();
    if (threadIdx.x < OUTC_) {
        const float invn = 1.f / (float)(N_ * S_);
        float mean = tot[threadIdx.x] * invn;
        float var = tot[60 + threadIdx.x] * invn - mean * mean;
        float sc = gamma[threadIdx.x] * rsqrtf(var + BN_EPS);
        scl[threadIdx.x] = sc;
        shf[threadIdx.x] = beta[threadIdx.x] - mean * sc;
    }
}

// ---------------- kernel E: in-place BN apply + ReLU ----------------
__global__ void k_apply(float* __restrict__ y, const float* __restrict__ scl,
                        const float* __restrict__ shf) {
    int idx = blockIdx.x * 256 + threadIdx.x;          // float4 index
    int o = (idx >> 12) % OUTC_;
    float4 v = ((const float4*)y)[idx];
    float a = scl[o], b = shf[o];
    v.x = fmaxf(v.x * a + b, 0.f);
    v.y = fmaxf(v.y * a + b, 0.f);
    v.z = fmaxf(v.z * a + b, 0.f);
    v.w = fmaxf(v.w * a + b, 0.f);
    ((float4*)y)[idx] = v;
}

extern "C" void kernel_launch(void* const* d_in, const int* in_sizes, int n_in,
                              void* d_out, int out_size, void* d_ws, size_t ws_size,
                              hipStream_t stream) {
    const float* p_fea = (const float*)d_in[0];
    const float* p_seg = (const float*)d_in[1];
    const float* Wq    = (const float*)d_in[2];
    const float* bq    = (const float*)d_in[3];
    const float* Wk    = (const float*)d_in[4];
    const float* bk    = (const float*)d_in[5];
    const float* Wp    = (const float*)d_in[6];
    const float* gamma = (const float*)d_in[7];
    const float* beta  = (const float*)d_in[8];

    float* ws   = (float*)d_ws;
    float* pp   = ws + OFF_PP;
    float* dp   = ws + OFF_DP;
    float* eb   = ws + OFF_EB;
    float* wb16 = ws + OFF_WB16;
    float* m2b  = ws + OFF_M2B;
    float* att  = ws + OFF_ATT;
    float* part = ws + OFF_PART;
    float* scl  = ws + OFF_SCL;
    float* shf  = ws + OFF_SHF;
    float* ybuf = (float*)d_out;

    k_att<<<256, 256, 0, stream>>>(p_seg, att, dp);
    k_num<<<1024, 256, 0, stream>>>(p_fea, att, pp);
    k_center<<<8, 256, 0, stream>>>(pp, dp, Wq, bq, Wk, bk, Wp, eb, m2b, wb16);
    k_main<<<1024, 256, 0, stream>>>(p_fea, wb16, eb, m2b, ybuf, part);
    k_bn<<<1, 512, 0, stream>>>(part, gamma, beta, scl, shf);
    k_apply<<<(N_ * OUTC_ * S_ / 4) / 256, 256, 0, stream>>>(ybuf, scl, shf);
}

// Round 12
// 151.504 us; speedup vs baseline: 2.3446x; 1.0359x over previous
//
#include <hip/hip_runtime.h>
#include <hip/hip_bf16.h>

#define N_    8
#define C_    256
#define K_    7
#define HID_  10
#define OUTC_ 60
#define S_    16384
#define BN_EPS 1e-5f

// ---- workspace layout (float offsets, all 16B-aligned) ----
#define OFF_PP     0        // pool partials: [n][qt4][oct32][64] = 65536
#define OFF_DP     65536    // den partials:  [n*32+t][8] = 2048
#define OFF_EB     67584    // 64
#define OFF_WB16   67648    // bf16 weight frag images: 8n x 24576 ush = 98304 fl
#define OFF_M2B    165952   // bf16 M2 images: 8n x 640 ush = 2560 fl
#define OFF_ATT    168512   // bf16 att: N*K*S ush = 917504 ush = 458752 fl
#define OFF_PART   627264   // 1024*120 = 122880
#define OFF_SCL    750144   // 64
#define OFF_SHF    750208   // 64
// total ~750272 floats ~= 3.0 MB

#define GLDS(g, l) __builtin_amdgcn_global_load_lds( \
    (const __attribute__((address_space(1))) unsigned int*)(g), \
    (__attribute__((address_space(3))) unsigned int*)(l), 16, 0, 0)

typedef __attribute__((ext_vector_type(8))) short bfrag;   // 8 bf16 = 4 VGPR
typedef __attribute__((ext_vector_type(4))) float f32x4;   // MFMA acc

static __device__ __forceinline__ unsigned short f2bf(float f) {
    __hip_bfloat16 h = __float2bfloat16(f);
    return *reinterpret_cast<unsigned short*>(&h);
}
static __device__ __forceinline__ float bfh2f(unsigned int u) {   // high 16 bits
    return __builtin_bit_cast(float, u & 0xffff0000u);
}
static __device__ __forceinline__ float bfl2f(unsigned int u) {   // low 16 bits
    return __builtin_bit_cast(float, u << 16);
}

// -------- kernel A0: class softmax (once per pixel) -> bf16 att + den partials ----
__global__ void __launch_bounds__(256) k_att(
        const float* __restrict__ seg, unsigned short* __restrict__ att16,
        float* __restrict__ dp) {
    int b = blockIdx.x;
    int lin = (b & 7) * 32 + (b >> 3);
    int n = lin >> 5, t = lin & 31;
    int tid = threadIdx.x;
    const float* sp = seg + (size_t)n * K_ * S_ + t * 512 + tid * 2;
    unsigned short* ap = att16 + (size_t)n * K_ * S_ + t * 512 + tid * 2;

    float2 e[K_];
    float mx = -1e30f, my = -1e30f;
#pragma unroll
    for (int k = 0; k < K_; k++) {
        e[k] = *(const float2*)(sp + (size_t)k * S_);
        mx = fmaxf(mx, e[k].x); my = fmaxf(my, e[k].y);
    }
    float sx = 0.f, sy = 0.f;
#pragma unroll
    for (int k = 0; k < K_; k++) {
        e[k].x = __expf(e[k].x - mx); sx += e[k].x;
        e[k].y = __expf(e[k].y - my); sy += e[k].y;
    }
    float ix = 1.f / sx, iy = 1.f / sy;
    float dsum[K_];
#pragma unroll
    for (int k = 0; k < K_; k++) {
        float ax = e[k].x * ix, ay = e[k].y * iy;
        *(unsigned int*)(ap + (size_t)k * S_) =
            (unsigned int)f2bf(ax) | ((unsigned int)f2bf(ay) << 16);
        dsum[k] = ax + ay;        // den from fp32 (pre-quantization)
    }
    __shared__ float red[4][K_];
    int lane = tid & 63, wv = tid >> 6;
#pragma unroll
    for (int k = 0; k < K_; k++) {
        float v = dsum[k];
        for (int off = 32; off; off >>= 1) v += __shfl_xor(v, off, 64);
        if (lane == 0) red[wv][k] = v;
    }
    __syncthreads();
    if (tid < K_)
        dp[((size_t)n * 32 + t) * 8 + tid] =
            red[0][tid] + red[1][tid] + red[2][tid] + red[3][tid];
}

// ---------------- kernel A1: pooling GEMM (bf16 att, 1024 blocks) ----------------
__global__ void __launch_bounds__(256) k_num(
        const float* __restrict__ fea, const unsigned short* __restrict__ att16,
        float* __restrict__ pp) {
    int b = blockIdx.x;
    int lin = (b & 7) * 128 + (b >> 3);
    int n = lin >> 7, rr = lin & 127;
    int oct = rr >> 2, qt = rr & 3, c0 = oct * 8;
    int tid = threadIdx.x;
    const unsigned short* ap = att16 + (size_t)n * K_ * S_ + qt * 4096 + tid * 4;
    const float* fp = fea + ((size_t)n * C_ + c0) * S_ + qt * 4096 + tid * 4;

    float acc[8][K_] = {};
#pragma unroll 2
    for (int it = 0; it < 4; it++) {
        int s = it * 1024;
        float4 av[K_], fv[8];
#pragma unroll
        for (int k = 0; k < K_; k++) {
            uint2 wa = *(const uint2*)(ap + (size_t)k * S_ + s);
            av[k] = make_float4(bfl2f(wa.x), bfh2f(wa.x), bfl2f(wa.y), bfh2f(wa.y));
        }
#pragma unroll
        for (int c = 0; c < 8; c++) fv[c] = *(const float4*)(fp + (size_t)c * S_ + s);
#pragma unroll
        for (int c = 0; c < 8; c++)
#pragma unroll
            for (int k = 0; k < K_; k++)
                acc[c][k] += fv[c].x*av[k].x + fv[c].y*av[k].y
                           + fv[c].z*av[k].z + fv[c].w*av[k].w;
    }
    __shared__ float red[4][56];
    int lane = tid & 63, wv = tid >> 6;
#pragma unroll
    for (int i = 0; i < 56; i++) {
        float v = acc[i / K_][i % K_];
        for (int off = 32; off; off >>= 1) v += __shfl_xor(v, off, 64);
        if (lane == 0) red[wv][i] = v;
    }
    __syncthreads();
    if (tid < 56)
        pp[(((size_t)n * 4 + qt) * 32 + oct) * 64 + tid] =
            red[0][tid] + red[1][tid] + red[2][tid] + red[3][tid];
}

// ---- kernel B: reduce partials -> p_center -> bf16 weight/M2 frag images ----
// 64 blocks: 8 per n (pc/ql replicated, output work sliced)
__global__ void k_center(const float* __restrict__ pp, const float* __restrict__ dp,
                         const float* __restrict__ Wq, const float* __restrict__ bq,
                         const float* __restrict__ Wk, const float* __restrict__ bk,
                         const float* __restrict__ Wp,
                         float* __restrict__ eb, float* __restrict__ m2b,
                         float* __restrict__ wb16) {
    int n = blockIdx.x >> 3, j = blockIdx.x & 7;
    int tid = threadIdx.x;
    __shared__ float pc[C_ * K_];     // [c][k]
    __shared__ float ql[HID_ * K_];   // [o][k]
    __shared__ float dinv[K_];
    if (tid < K_) {
        float d = 0.f;
        for (int t = 0; t < 32; t++) d += dp[((size_t)n * 32 + t) * 8 + tid];
        dinv[tid] = 1.f / d;
    }
    __syncthreads();
    for (int i = tid; i < C_ * K_; i += 256) {
        int c = i / K_, k = i - c * K_;
        int oct = c >> 3, ci = c & 7;
        float v = 0.f;
#pragma unroll
        for (int qt = 0; qt < 4; qt++)
            v += pp[(((size_t)n * 4 + qt) * 32 + oct) * 64 + ci * K_ + k];
        pc[i] = v * dinv[k];
    }
    __syncthreads();
    if (tid < HID_ * K_) {
        int o = tid / K_, k = tid % K_;
        float s = bq[o];
        for (int c = 0; c < C_; c++) s += Wq[o * C_ + c] * pc[c * K_ + k];
        ql[tid] = s;
    }
    __syncthreads();
    // bf16 weight image slice: this block covers i in [j*3072, (j+1)*3072)
    unsigned short* wp16 = (unsigned short*)wb16 + (size_t)n * 24576;
    for (int i = j * 3072 + tid; i < (j + 1) * 3072; i += 256) {
        int ch = i / 6144, r = i - ch * 6144;
        int o = r / 72, jj = r - o * 72;
        float v = 0.f;
        if (o < 80 && jj < 64) {
            int c = ch * 64 + jj;
            if (o < 60) v = Wp[o * 2 * C_ + c];
            else if (o < 67) {
                int k = o - 60;
                for (int o2 = 0; o2 < HID_; o2++) v += ql[o2 * K_ + k] * Wk[o2 * C_ + c];
            }
        }
        wp16[i] = f2bf(v);
    }
    // bf16 M2 image slice: entries [j*80, (j+1)*80)
    unsigned short* mp16 = (unsigned short*)m2b + (size_t)n * 640;
    if (tid < 80) {
        int i = j * 80 + tid;
        int o = i >> 3, k = i & 7;
        float v = 0.f;
        if (k < 7 && o < 60) {
            for (int c = 0; c < C_; c++) v += Wp[o * 2 * C_ + C_ + c] * pc[c * K_ + k];
        }
        mp16[i] = f2bf(v);
    }
    if (j == 0 && tid < K_) {
        float s = 0.f;
        for (int o = 0; o < HID_; o++) s += ql[o * K_ + tid] * bk[o];
        eb[n * K_ + tid] = s;
    }
}

// ---------------- kernel C: MFMA fused energy/softmax/projection ----------------
// (round-9 proven form) 1024 blocks xcd-chunked; 128 px/block; 4 waves.
__global__ void __launch_bounds__(256) k_main(
        const float* __restrict__ fea, const float* __restrict__ wb16,
        const float* __restrict__ ebias, const float* __restrict__ m2b,
        float* __restrict__ y, float* __restrict__ part) {
    int g = blockIdx.x;
    int lin = (g & 7) * 128 + (g >> 3);
    int n = lin >> 7, tile = lin & 127;
    int tid = threadIdx.x, lane = tid & 63, wv = tid >> 6;
    int r15 = lane & 15, kg = (lane >> 4) << 3, pg = (lane >> 4) << 2;

    __shared__ unsigned short wlds[2][6144];   // weight chunk images (24 KB)
    __shared__ unsigned short feaT[2][9216];   // [128 px][72 c] bf16 (36 KB)
    __shared__ unsigned short abf[128 * 8];    // attention [px][8k] bf16
    __shared__ unsigned short m2l[640];        // M2 [80][8] bf16
    __shared__ float att_e[K_][128];
    __shared__ float ebl[8];
    __shared__ float redm[4][80];
    __shared__ float redq[4][80];

    const unsigned int* wsrc = (const unsigned int*)wb16 + (size_t)n * 12288;
    const unsigned int* m2s  = (const unsigned int*)m2b + (size_t)n * 320;
    for (int i = tid; i < 320; i += 256) ((unsigned int*)m2l)[i] = m2s[i];
    if (tid < K_) ebl[tid] = ebias[n * K_ + tid];

    const float* fbase = fea + (size_t)n * C_ * S_ + tile * 128;
    int cr2 = tid >> 3, h = tid & 7;           // c-pair + px-octant for staging

    f32x4 acc[5][2];
#pragma unroll
    for (int ot = 0; ot < 5; ot++) { acc[ot][0] = (f32x4)0.f; acc[ot][1] = (f32x4)0.f; }

    // prologue: stage weights chunk 0 (GLDS) + fea chunk 0 (reg -> bf16 transpose)
#pragma unroll
    for (int rnd = 0; rnd < 3; rnd++)
        GLDS(wsrc + rnd * 1024 + wv * 256 + lane * 4,
             &((unsigned int*)wlds[0])[rnd * 1024 + wv * 256]);
    {
        const float* bp = fbase + (size_t)(cr2 * 2) * S_ + h * 16;
        float4 v0[4], v1[4];
#pragma unroll
        for (int i = 0; i < 4; i++) v0[i] = *(const float4*)(bp + i * 4);
#pragma unroll
        for (int i = 0; i < 4; i++) v1[i] = *(const float4*)(bp + S_ + i * 4);
        unsigned int* dst = (unsigned int*)feaT[0];
#pragma unroll
        for (int i = 0; i < 4; i++)
#pragma unroll
            for (int e = 0; e < 4; e++) {
                int px = h * 16 + i * 4 + e;
                dst[px * 36 + cr2] = (unsigned int)f2bf(((const float*)&v0[i])[e])
                                   | ((unsigned int)f2bf(((const float*)&v1[i])[e]) << 16);
            }
    }
    asm volatile("s_waitcnt vmcnt(0) lgkmcnt(0)" ::: "memory");
    __builtin_amdgcn_s_barrier();

#pragma unroll
    for (int ch = 0; ch < 4; ch++) {
        int bb = ch & 1;
        float4 s0[4], s1[4];
        if (ch < 3) {
#pragma unroll
            for (int rnd = 0; rnd < 3; rnd++)
                GLDS(wsrc + (ch + 1) * 3072 + rnd * 1024 + wv * 256 + lane * 4,
                     &((unsigned int*)wlds[bb ^ 1])[rnd * 1024 + wv * 256]);
            const float* bp = fbase + (size_t)((ch + 1) * 64 + cr2 * 2) * S_ + h * 16;
#pragma unroll
            for (int i = 0; i < 4; i++) s0[i] = *(const float4*)(bp + i * 4);
#pragma unroll
            for (int i = 0; i < 4; i++) s1[i] = *(const float4*)(bp + S_ + i * 4);
        }
        // MFMA on current chunk: 2 K-steps x 5 out-tiles x 2 px-tiles
        const unsigned short* fb = feaT[bb];
        const unsigned short* wb = wlds[bb];
#pragma unroll
        for (int ks = 0; ks < 2; ks++) {
            bfrag a0 = *(const bfrag*)&fb[(wv * 32 + r15) * 72 + ks * 32 + kg];
            bfrag a1 = *(const bfrag*)&fb[(wv * 32 + 16 + r15) * 72 + ks * 32 + kg];
#pragma unroll
            for (int ot = 0; ot < 5; ot++) {
                bfrag b = *(const bfrag*)&wb[(ot * 16 + r15) * 72 + ks * 32 + kg];
                acc[ot][0] = __builtin_amdgcn_mfma_f32_16x16x32_bf16(a0, b, acc[ot][0], 0, 0, 0);
                acc[ot][1] = __builtin_amdgcn_mfma_f32_16x16x32_bf16(a1, b, acc[ot][1], 0, 0, 0);
            }
        }
        if (ch < 3) {   // transpose-write next fea chunk (vmcnt wait lands here)
            unsigned int* dst = (unsigned int*)feaT[bb ^ 1];
#pragma unroll
            for (int i = 0; i < 4; i++)
#pragma unroll
                for (int e = 0; e < 4; e++) {
                    int px = h * 16 + i * 4 + e;
                    dst[px * 36 + cr2] = (unsigned int)f2bf(((const float*)&s0[i])[e])
                                       | ((unsigned int)f2bf(((const float*)&s1[i])[e]) << 16);
                }
        }
        asm volatile("s_waitcnt vmcnt(0) lgkmcnt(0)" ::: "memory");
        __builtin_amdgcn_s_barrier();
    }

    // energies: cols 60..63 in out-tile 3 (local 12..15), 64..66 in tile 4 (local 0..2)
    if (r15 >= 12) {
        int k = r15 - 12;
#pragma unroll
        for (int pxt = 0; pxt < 2; pxt++)
#pragma unroll
            for (int r = 0; r < 4; r++)
                att_e[k][wv * 32 + pxt * 16 + pg + r] = acc[3][pxt][r];
    }
    if (r15 < 3) {
        int k = 4 + r15;
#pragma unroll
        for (int pxt = 0; pxt < 2; pxt++)
#pragma unroll
            for (int r = 0; r < 4; r++)
                att_e[k][wv * 32 + pxt * 16 + pg + r] = acc[4][pxt][r];
    }
    __syncthreads();
    if (tid < 128) {   // per-px class softmax -> bf16 attention fragments
        float e[K_], mx = -1e30f;
#pragma unroll
        for (int k = 0; k < K_; k++) { e[k] = att_e[k][tid] + ebl[k]; mx = fmaxf(mx, e[k]); }
        float sum = 0.f;
#pragma unroll
        for (int k = 0; k < K_; k++) { e[k] = __expf(e[k] - mx); sum += e[k]; }
        float inv = 1.f / sum;
        unsigned int* ab = (unsigned int*)abf;
        ab[tid * 4 + 0] = (unsigned int)f2bf(e[0] * inv) | ((unsigned int)f2bf(e[1] * inv) << 16);
        ab[tid * 4 + 1] = (unsigned int)f2bf(e[2] * inv) | ((unsigned int)f2bf(e[3] * inv) << 16);
        ab[tid * 4 + 2] = (unsigned int)f2bf(e[4] * inv) | ((unsigned int)f2bf(e[5] * inv) << 16);
        ab[tid * 4 + 3] = (unsigned int)f2bf(e[6] * inv);
    }
    __syncthreads();

    // y += M2 @ attention  (one K=32 MFMA, k>=8 lanes contribute zero)
    bfrag az = (bfrag)(short)0;
    bfrag a20 = az, a21 = az;
    if (lane < 16) {
        a20 = *(const bfrag*)&abf[(wv * 32 + r15) * 8];
        a21 = *(const bfrag*)&abf[(wv * 32 + 16 + r15) * 8];
    }
#pragma unroll
    for (int ot = 0; ot < 5; ot++) {
        bfrag b2 = az;
        if (lane < 16) b2 = *(const bfrag*)&m2l[(ot * 16 + r15) * 8];
        acc[ot][0] = __builtin_amdgcn_mfma_f32_16x16x32_bf16(a20, b2, acc[ot][0], 0, 0, 0);
        acc[ot][1] = __builtin_amdgcn_mfma_f32_16x16x32_bf16(a21, b2, acc[ot][1], 0, 0, 0);
    }

    // store pre-BN y (cols < 60) + per-block BN partials
    float* ybase = y + (size_t)n * OUTC_ * S_ + tile * 128 + wv * 32 + pg;
#pragma unroll
    for (int ot = 0; ot < 5; ot++) {
        int o = ot * 16 + r15;
        float sm_ = 0.f, sq_ = 0.f;
#pragma unroll
        for (int pxt = 0; pxt < 2; pxt++) {
            f32x4 v = acc[ot][pxt];
            if (o < OUTC_)
                *(f32x4*)(ybase + (size_t)o * S_ + pxt * 16) = v;
            sm_ += v[0] + v[1] + v[2] + v[3];
            sq_ += v[0]*v[0] + v[1]*v[1] + v[2]*v[2] + v[3]*v[3];
        }
        sm_ += __shfl_xor(sm_, 16, 64); sm_ += __shfl_xor(sm_, 32, 64);
        sq_ += __shfl_xor(sq_, 16, 64); sq_ += __shfl_xor(sq_, 32, 64);
        if (lane < 16) { redm[wv][ot * 16 + lane] = sm_; redq[wv][ot * 16 + lane] = sq_; }
    }
    __syncthreads();
    if (tid < 120) {
        float s;
        if (tid < OUTC_)
            s = redm[0][tid] + redm[1][tid] + redm[2][tid] + redm[3][tid];
        else {
            int o = tid - OUTC_;
            s = redq[0][o] + redq[1][o] + redq[2][o] + redq[3][o];
        }
        part[(size_t)g * 120 + tid] = s;
    }
}

// ---------------- kernel D: BN statistics ----------------
__global__ void k_bn(const float* __restrict__ part, const float* __restrict__ gamma,
                     const float* __restrict__ beta, float* __restrict__ scl,
                     float* __restrict__ shf) {
    int t = threadIdx.x & 127, q = threadIdx.x >> 7;   // 512 threads
    __shared__ float red[4][120];
    __shared__ float tot[120];
    if (t < 120) {
        float s = 0.f;
        for (int b = q * 256; b < q * 256 + 256; b++) s += part[(size_t)b * 120 + t];
        red[q][t] = s;
    }
    __syncthreads();
    if (threadIdx.x < 120)
        tot[threadIdx.x] = red[0][threadIdx.x] + red[1][threadIdx.x] +
                           red[2][threadIdx.x] + red[3][threadIdx.x];
    __syncthreads();
    if (threadIdx.x < OUTC_) {
        const float invn = 1.f / (float)(N_ * S_);
        float mean = tot[threadIdx.x] * invn;
        float var = tot[60 + threadIdx.x] * invn - mean * mean;
        float sc = gamma[threadIdx.x] * rsqrtf(var + BN_EPS);
        scl[threadIdx.x] = sc;
        shf[threadIdx.x] = beta[threadIdx.x] - mean * sc;
    }
}

// ---------------- kernel E: in-place BN apply + ReLU ----------------
__global__ void k_apply(float* __restrict__ y, const float* __restrict__ scl,
                        const float* __restrict__ shf) {
    int idx = blockIdx.x * 256 + threadIdx.x;          // float4 index
    int o = (idx >> 12) % OUTC_;
    float4 v = ((const float4*)y)[idx];
    float a = scl[o], b = shf[o];
    v.x = fmaxf(v.x * a + b, 0.f);
    v.y = fmaxf(v.y * a + b, 0.f);
    v.z = fmaxf(v.z * a + b, 0.f);
    v.w = fmaxf(v.w * a + b, 0.f);
    ((float4*)y)[idx] = v;
}

extern "C" void kernel_launch(void* const* d_in, const int* in_sizes, int n_in,
                              void* d_out, int out_size, void* d_ws, size_t ws_size,
                              hipStream_t stream) {
    const float* p_fea = (const float*)d_in[0];
    const float* p_seg = (const float*)d_in[1];
    const float* Wq    = (const float*)d_in[2];
    const float* bq    = (const float*)d_in[3];
    const float* Wk    = (const float*)d_in[4];
    const float* bk    = (const float*)d_in[5];
    const float* Wp    = (const float*)d_in[6];
    const float* gamma = (const float*)d_in[7];
    const float* beta  = (const float*)d_in[8];

    float* ws   = (float*)d_ws;
    float* pp   = ws + OFF_PP;
    float* dp   = ws + OFF_DP;
    float* eb   = ws + OFF_EB;
    float* wb16 = ws + OFF_WB16;
    float* m2b  = ws + OFF_M2B;
    unsigned short* att16 = (unsigned short*)(ws + OFF_ATT);
    float* part = ws + OFF_PART;
    float* scl  = ws + OFF_SCL;
    float* shf  = ws + OFF_SHF;
    float* ybuf = (float*)d_out;

    k_att<<<256, 256, 0, stream>>>(p_seg, att16, dp);
    k_num<<<1024, 256, 0, stream>>>(p_fea, att16, pp);
    k_center<<<64, 256, 0, stream>>>(pp, dp, Wq, bq, Wk, bk, Wp, eb, m2b, wb16);
    k_main<<<1024, 256, 0, stream>>>(p_fea, wb16, eb, m2b, ybuf, part);
    k_bn<<<1, 512, 0, stream>>>(part, gamma, beta, scl, shf);
    k_apply<<<(N_ * OUTC_ * S_ / 4) / 256, 256, 0, stream>>>(ybuf, scl, shf);
}

// Round 13
// 117.741 us; speedup vs baseline: 3.0170x; 1.2868x over previous
//
#include <hip/hip_runtime.h>
#include <hip/hip_bf16.h>

#define N_    8
#define C_    256
#define K_    7
#define HID_  10
#define OUTC_ 60
#define S_    16384
#define BN_EPS 1e-5f

// ---- workspace layout (float offsets, all 16B-aligned) ----
#define OFF_PP     0        // pool partials: [512 slice][256 c][8 k] = 1048576
#define OFF_DP     1048576  // den partials: [512 slice][8] = 4096
#define OFF_EB     1052672  // 64
#define OFF_WB16   1052736  // bf16 weight frag images: 8n x 24576 ush = 98304 fl
#define OFF_M2B    1151040  // bf16 M2 images: 8n x 640 ush = 2560 fl
#define OFF_PART   1153600  // 1024*120 = 122880
#define OFF_SCL    1276480  // 64
#define OFF_SHF    1276544  // 64
// total ~1276608 floats ~= 5.1 MB

#define GLDS(g, l) __builtin_amdgcn_global_load_lds( \
    (const __attribute__((address_space(1))) unsigned int*)(g), \
    (__attribute__((address_space(3))) unsigned int*)(l), 16, 0, 0)

typedef __attribute__((ext_vector_type(8))) short bfrag;   // 8 bf16 = 4 VGPR
typedef __attribute__((ext_vector_type(4))) float f32x4;   // MFMA acc

static __device__ __forceinline__ unsigned short f2bf(float f) {
    __hip_bfloat16 h = __float2bfloat16(f);
    return *reinterpret_cast<unsigned short*>(&h);
}

// -------- kernel A: fused class-softmax + MFMA pooling GEMM ----------------
// 512 blocks xcd-chunked; block = (n, 256-px slice).
// num[c][k] += fea[c][s] * att[k][s] via mfma_16x16x32_bf16 (A=fea, B=attT).
__global__ void __launch_bounds__(256) k_pool(
        const float* __restrict__ fea, const float* __restrict__ seg,
        float* __restrict__ pp, float* __restrict__ dp) {
    int g = blockIdx.x;
    int lin = (g & 7) * 64 + (g >> 3);
    int n = lin >> 6, sl = lin & 63;
    int tid = threadIdx.x, lane = tid & 63, wv = tid >> 6;
    int r15 = lane & 15, kg = (lane >> 4) << 3, pg = (lane >> 4) << 2;
    int px0 = sl * 256;

    __shared__ unsigned short attT[16 * 256];       // [k][px] bf16 (8 KB)
    __shared__ unsigned short feaB[2][256 * 32];    // [c][px] bf16 (2x16 KB)
    __shared__ float red[4][8];

    // phase 1: per-px class softmax (thread = px), den partials (fp32)
    {
        const float* sp = seg + (size_t)n * K_ * S_ + px0 + tid;
        float e[K_], mx = -1e30f;
#pragma unroll
        for (int k = 0; k < K_; k++) { e[k] = sp[(size_t)k * S_]; mx = fmaxf(mx, e[k]); }
        float sum = 0.f;
#pragma unroll
        for (int k = 0; k < K_; k++) { e[k] = __expf(e[k] - mx); sum += e[k]; }
        float inv = 1.f / sum;
#pragma unroll
        for (int k = 0; k < K_; k++) {
            e[k] *= inv;
            attT[k * 256 + tid] = f2bf(e[k]);
        }
#pragma unroll
        for (int k = 0; k < K_; k++) {
            float v = e[k];
            for (int off = 32; off; off >>= 1) v += __shfl_xor(v, off, 64);
            if (lane == 0) red[wv][k] = v;
        }
    }

    const float* fb = fea + (size_t)n * C_ * S_ + px0;
    int pq4 = (tid & 7) * 4;                        // px-quad within 32-px chunk
    int crow = tid >> 3;                            // c row offset within round

    // stage chunk 0
    {
        float4 s[8];
#pragma unroll
        for (int rr = 0; rr < 8; rr++)
            s[rr] = *(const float4*)(fb + (size_t)(rr * 32 + crow) * S_ + pq4);
#pragma unroll
        for (int rr = 0; rr < 8; rr++) {
            unsigned int u0 = (unsigned int)f2bf(s[rr].x) | ((unsigned int)f2bf(s[rr].y) << 16);
            unsigned int u1 = (unsigned int)f2bf(s[rr].z) | ((unsigned int)f2bf(s[rr].w) << 16);
            *(uint2*)&feaB[0][(rr * 32 + crow) * 32 + pq4] = make_uint2(u0, u1);
        }
    }
    __syncthreads();
    if (tid < K_)
        dp[(size_t)lin * 8 + tid] = red[0][tid] + red[1][tid] + red[2][tid] + red[3][tid];

    f32x4 acc[4];
#pragma unroll
    for (int mt = 0; mt < 4; mt++) acc[mt] = (f32x4)0.f;

#pragma unroll
    for (int ch = 0; ch < 8; ch++) {
        int cur = ch & 1;
        float4 s[8];
        if (ch < 7) {
#pragma unroll
            for (int rr = 0; rr < 8; rr++)
                s[rr] = *(const float4*)(fb + (size_t)(rr * 32 + crow) * S_ + (ch + 1) * 32 + pq4);
        }
        // MFMA on current chunk: 4 c-tiles per wave, K=32 px
        bfrag b = *(const bfrag*)&attT[r15 * 256 + ch * 32 + kg];
#pragma unroll
        for (int mt = 0; mt < 4; mt++) {
            bfrag a = *(const bfrag*)&feaB[cur][(wv * 64 + mt * 16 + r15) * 32 + kg];
            acc[mt] = __builtin_amdgcn_mfma_f32_16x16x32_bf16(a, b, acc[mt], 0, 0, 0);
        }
        if (ch < 7) {
#pragma unroll
            for (int rr = 0; rr < 8; rr++) {
                unsigned int u0 = (unsigned int)f2bf(s[rr].x) | ((unsigned int)f2bf(s[rr].y) << 16);
                unsigned int u1 = (unsigned int)f2bf(s[rr].z) | ((unsigned int)f2bf(s[rr].w) << 16);
                *(uint2*)&feaB[cur ^ 1][(rr * 32 + crow) * 32 + pq4] = make_uint2(u0, u1);
            }
        }
        __syncthreads();
    }

    // store per-slice num partials: D col = k (r15), row = c (pg+r within tile)
    if (r15 < K_) {
#pragma unroll
        for (int mt = 0; mt < 4; mt++) {
#pragma unroll
            for (int r = 0; r < 4; r++) {
                int c = wv * 64 + mt * 16 + pg + r;
                pp[((size_t)lin * 256 + c) * 8 + r15] = acc[mt][r];
            }
        }
    }
}

// ---- kernel B: reduce partials -> p_center -> bf16 weight/M2 frag images ----
// 64 blocks: 8 per n (pc/ql replicated, output work sliced)
__global__ void k_center(const float* __restrict__ pp, const float* __restrict__ dp,
                         const float* __restrict__ Wq, const float* __restrict__ bq,
                         const float* __restrict__ Wk, const float* __restrict__ bk,
                         const float* __restrict__ Wp,
                         float* __restrict__ eb, float* __restrict__ m2b,
                         float* __restrict__ wb16) {
    int n = blockIdx.x >> 3, j = blockIdx.x & 7;
    int tid = threadIdx.x;
    __shared__ float pc[C_ * K_];     // [c][k]
    __shared__ float ql[HID_ * K_];   // [o][k]
    __shared__ float dinv[K_];
    if (tid < K_) {
        float d = 0.f;
        for (int s = 0; s < 64; s++) d += dp[(size_t)(n * 64 + s) * 8 + tid];
        dinv[tid] = 1.f / d;
    }
    __syncthreads();
    for (int i = tid; i < C_ * K_; i += 256) {
        int c = i / K_, k = i - c * K_;
        float v = 0.f;
        for (int s = 0; s < 64; s++)
            v += pp[((size_t)(n * 64 + s) * 256 + c) * 8 + k];
        pc[i] = v * dinv[k];
    }
    __syncthreads();
    if (tid < HID_ * K_) {
        int o = tid / K_, k = tid % K_;
        float s = bq[o];
        for (int c = 0; c < C_; c++) s += Wq[o * C_ + c] * pc[c * K_ + k];
        ql[tid] = s;
    }
    __syncthreads();
    // bf16 weight image slice: this block covers i in [j*3072, (j+1)*3072)
    unsigned short* wp16 = (unsigned short*)wb16 + (size_t)n * 24576;
    for (int i = j * 3072 + tid; i < (j + 1) * 3072; i += 256) {
        int ch = i / 6144, r = i - ch * 6144;
        int o = r / 72, jj = r - o * 72;
        float v = 0.f;
        if (o < 80 && jj < 64) {
            int c = ch * 64 + jj;
            if (o < 60) v = Wp[o * 2 * C_ + c];
            else if (o < 67) {
                int k = o - 60;
                for (int o2 = 0; o2 < HID_; o2++) v += ql[o2 * K_ + k] * Wk[o2 * C_ + c];
            }
        }
        wp16[i] = f2bf(v);
    }
    // bf16 M2 image slice: entries [j*80, (j+1)*80)
    unsigned short* mp16 = (unsigned short*)m2b + (size_t)n * 640;
    if (tid < 80) {
        int i = j * 80 + tid;
        int o = i >> 3, k = i & 7;
        float v = 0.f;
        if (k < 7 && o < 60) {
            for (int c = 0; c < C_; c++) v += Wp[o * 2 * C_ + C_ + c] * pc[c * K_ + k];
        }
        mp16[i] = f2bf(v);
    }
    if (j == 0 && tid < K_) {
        float s = 0.f;
        for (int o = 0; o < HID_; o++) s += ql[o * K_ + tid] * bk[o];
        eb[n * K_ + tid] = s;
    }
}

// ---------------- kernel C: MFMA fused energy/softmax/projection ----------------
// (round-9 proven form) 1024 blocks xcd-chunked; 128 px/block; 4 waves.
__global__ void __launch_bounds__(256) k_main(
        const float* __restrict__ fea, const float* __restrict__ wb16,
        const float* __restrict__ ebias, const float* __restrict__ m2b,
        float* __restrict__ y, float* __restrict__ part) {
    int g = blockIdx.x;
    int lin = (g & 7) * 128 + (g >> 3);
    int n = lin >> 7, tile = lin & 127;
    int tid = threadIdx.x, lane = tid & 63, wv = tid >> 6;
    int r15 = lane & 15, kg = (lane >> 4) << 3, pg = (lane >> 4) << 2;

    __shared__ unsigned short wlds[2][6144];   // weight chunk images (24 KB)
    __shared__ unsigned short feaT[2][9216];   // [128 px][72 c] bf16 (36 KB)
    __shared__ unsigned short abf[128 * 8];    // attention [px][8k] bf16
    __shared__ unsigned short m2l[640];        // M2 [80][8] bf16
    __shared__ float att_e[K_][128];
    __shared__ float ebl[8];
    __shared__ float redm[4][80];
    __shared__ float redq[4][80];

    const unsigned int* wsrc = (const unsigned int*)wb16 + (size_t)n * 12288;
    const unsigned int* m2s  = (const unsigned int*)m2b + (size_t)n * 320;
    for (int i = tid; i < 320; i += 256) ((unsigned int*)m2l)[i] = m2s[i];
    if (tid < K_) ebl[tid] = ebias[n * K_ + tid];

    const float* fbase = fea + (size_t)n * C_ * S_ + tile * 128;
    int cr2 = tid >> 3, h = tid & 7;           // c-pair + px-octant for staging

    f32x4 acc[5][2];
#pragma unroll
    for (int ot = 0; ot < 5; ot++) { acc[ot][0] = (f32x4)0.f; acc[ot][1] = (f32x4)0.f; }

    // prologue: stage weights chunk 0 (GLDS) + fea chunk 0 (reg -> bf16 transpose)
#pragma unroll
    for (int rnd = 0; rnd < 3; rnd++)
        GLDS(wsrc + rnd * 1024 + wv * 256 + lane * 4,
             &((unsigned int*)wlds[0])[rnd * 1024 + wv * 256]);
    {
        const float* bp = fbase + (size_t)(cr2 * 2) * S_ + h * 16;
        float4 v0[4], v1[4];
#pragma unroll
        for (int i = 0; i < 4; i++) v0[i] = *(const float4*)(bp + i * 4);
#pragma unroll
        for (int i = 0; i < 4; i++) v1[i] = *(const float4*)(bp + S_ + i * 4);
        unsigned int* dst = (unsigned int*)feaT[0];
#pragma unroll
        for (int i = 0; i < 4; i++)
#pragma unroll
            for (int e = 0; e < 4; e++) {
                int px = h * 16 + i * 4 + e;
                dst[px * 36 + cr2] = (unsigned int)f2bf(((const float*)&v0[i])[e])
                                   | ((unsigned int)f2bf(((const float*)&v1[i])[e]) << 16);
            }
    }
    asm volatile("s_waitcnt vmcnt(0) lgkmcnt(0)" ::: "memory");
    __builtin_amdgcn_s_barrier();

#pragma unroll
    for (int ch = 0; ch < 4; ch++) {
        int bb = ch & 1;
        float4 s0[4], s1[4];
        if (ch < 3) {
#pragma unroll
            for (int rnd = 0; rnd < 3; rnd++)
                GLDS(wsrc + (ch + 1) * 3072 + rnd * 1024 + wv * 256 + lane * 4,
                     &((unsigned int*)wlds[bb ^ 1])[rnd * 1024 + wv * 256]);
            const float* bp = fbase + (size_t)((ch + 1) * 64 + cr2 * 2) * S_ + h * 16;
#pragma unroll
            for (int i = 0; i < 4; i++) s0[i] = *(const float4*)(bp + i * 4);
#pragma unroll
            for (int i = 0; i < 4; i++) s1[i] = *(const float4*)(bp + S_ + i * 4);
        }
        // MFMA on current chunk: 2 K-steps x 5 out-tiles x 2 px-tiles
        const unsigned short* fb = feaT[bb];
        const unsigned short* wb = wlds[bb];
#pragma unroll
        for (int ks = 0; ks < 2; ks++) {
            bfrag a0 = *(const bfrag*)&fb[(wv * 32 + r15) * 72 + ks * 32 + kg];
            bfrag a1 = *(const bfrag*)&fb[(wv * 32 + 16 + r15) * 72 + ks * 32 + kg];
#pragma unroll
            for (int ot = 0; ot < 5; ot++) {
                bfrag b = *(const bfrag*)&wb[(ot * 16 + r15) * 72 + ks * 32 + kg];
                acc[ot][0] = __builtin_amdgcn_mfma_f32_16x16x32_bf16(a0, b, acc[ot][0], 0, 0, 0);
                acc[ot][1] = __builtin_amdgcn_mfma_f32_16x16x32_bf16(a1, b, acc[ot][1], 0, 0, 0);
            }
        }
        if (ch < 3) {   // transpose-write next fea chunk (vmcnt wait lands here)
            unsigned int* dst = (unsigned int*)feaT[bb ^ 1];
#pragma unroll
            for (int i = 0; i < 4; i++)
#pragma unroll
                for (int e = 0; e < 4; e++) {
                    int px = h * 16 + i * 4 + e;
                    dst[px * 36 + cr2] = (unsigned int)f2bf(((const float*)&s0[i])[e])
                                       | ((unsigned int)f2bf(((const float*)&s1[i])[e]) << 16);
                }
        }
        asm volatile("s_waitcnt vmcnt(0) lgkmcnt(0)" ::: "memory");
        __builtin_amdgcn_s_barrier();
    }

    // energies: cols 60..63 in out-tile 3 (local 12..15), 64..66 in tile 4 (local 0..2)
    if (r15 >= 12) {
        int k = r15 - 12;
#pragma unroll
        for (int pxt = 0; pxt < 2; pxt++)
#pragma unroll
            for (int r = 0; r < 4; r++)
                att_e[k][wv * 32 + pxt * 16 + pg + r] = acc[3][pxt][r];
    }
    if (r15 < 3) {
        int k = 4 + r15;
#pragma unroll
        for (int pxt = 0; pxt < 2; pxt++)
#pragma unroll
            for (int r = 0; r < 4; r++)
                att_e[k][wv * 32 + pxt * 16 + pg + r] = acc[4][pxt][r];
    }
    __syncthreads();
    if (tid < 128) {   // per-px class softmax -> bf16 attention fragments
        float e[K_], mx = -1e30f;
#pragma unroll
        for (int k = 0; k < K_; k++) { e[k] = att_e[k][tid] + ebl[k]; mx = fmaxf(mx, e[k]); }
        float sum = 0.f;
#pragma unroll
        for (int k = 0; k < K_; k++) { e[k] = __expf(e[k] - mx); sum += e[k]; }
        float inv = 1.f / sum;
        unsigned int* ab = (unsigned int*)abf;
        ab[tid * 4 + 0] = (unsigned int)f2bf(e[0] * inv) | ((unsigned int)f2bf(e[1] * inv) << 16);
        ab[tid * 4 + 1] = (unsigned int)f2bf(e[2] * inv) | ((unsigned int)f2bf(e[3] * inv) << 16);
        ab[tid * 4 + 2] = (unsigned int)f2bf(e[4] * inv) | ((unsigned int)f2bf(e[5] * inv) << 16);
        ab[tid * 4 + 3] = (unsigned int)f2bf(e[6] * inv);
    }
    __syncthreads();

    // y += M2 @ attention  (one K=32 MFMA, k>=8 lanes contribute zero)
    bfrag az = (bfrag)(short)0;
    bfrag a20 = az, a21 = az;
    if (lane < 16) {
        a20 = *(const bfrag*)&abf[(wv * 32 + r15) * 8];
        a21 = *(const bfrag*)&abf[(wv * 32 + 16 + r15) * 8];
    }
#pragma unroll
    for (int ot = 0; ot < 5; ot++) {
        bfrag b2 = az;
        if (lane < 16) b2 = *(const bfrag*)&m2l[(ot * 16 + r15) * 8];
        acc[ot][0] = __builtin_amdgcn_mfma_f32_16x16x32_bf16(a20, b2, acc[ot][0], 0, 0, 0);
        acc[ot][1] = __builtin_amdgcn_mfma_f32_16x16x32_bf16(a21, b2, acc[ot][1], 0, 0, 0);
    }

    // store pre-BN y (cols < 60) + per-block BN partials
    float* ybase = y + (size_t)n * OUTC_ * S_ + tile * 128 + wv * 32 + pg;
#pragma unroll
    for (int ot = 0; ot < 5; ot++) {
        int o = ot * 16 + r15;
        float sm_ = 0.f, sq_ = 0.f;
#pragma unroll
        for (int pxt = 0; pxt < 2; pxt++) {
            f32x4 v = acc[ot][pxt];
            if (o < OUTC_)
                *(f32x4*)(ybase + (size_t)o * S_ + pxt * 16) = v;
            sm_ += v[0] + v[1] + v[2] + v[3];
            sq_ += v[0]*v[0] + v[1]*v[1] + v[2]*v[2] + v[3]*v[3];
        }
        sm_ += __shfl_xor(sm_, 16, 64); sm_ += __shfl_xor(sm_, 32, 64);
        sq_ += __shfl_xor(sq_, 16, 64); sq_ += __shfl_xor(sq_, 32, 64);
        if (lane < 16) { redm[wv][ot * 16 + lane] = sm_; redq[wv][ot * 16 + lane] = sq_; }
    }
    __syncthreads();
    if (tid < 120) {
        float s;
        if (tid < OUTC_)
            s = redm[0][tid] + redm[1][tid] + redm[2][tid] + redm[3][tid];
        else {
            int o = tid - OUTC_;
            s = redq[0][o] + redq[1][o] + redq[2][o] + redq[3][o];
        }
        part[(size_t)g * 120 + tid] = s;
    }
}

// ---------------- kernel D: BN statistics ----------------
__global__ void k_bn(const float* __restrict__ part, const float* __restrict__ gamma,
                     const float* __restrict__ beta, float* __restrict__ scl,
                     float* __restrict__ shf) {
    int t = threadIdx.x & 127, q = threadIdx.x >> 7;   // 512 threads
    __shared__ float red[4][120];
    __shared__ float tot[120];
    if (t < 120) {
        float s = 0.f;
        for (int b = q * 256; b < q * 256 + 256; b++) s += part[(size_t)b * 120 + t];
        red[q][t] = s;
    }
    __syncthreads();
    if (threadIdx.x < 120)
        tot[threadIdx.x] = red[0][threadIdx.x] + red[1][threadIdx.x] +
                           red[2][threadIdx.x] + red[3][threadIdx.x];
    __syncthreads();
    if (threadIdx.x < OUTC_) {
        const float invn = 1.f / (float)(N_ * S_);
        float mean = tot[threadIdx.x] * invn;
        float var = tot[60 + threadIdx.x] * invn - mean * mean;
        float sc = gamma[threadIdx.x] * rsqrtf(var + BN_EPS);
        scl[threadIdx.x] = sc;
        shf[threadIdx.x] = beta[threadIdx.x] - mean * sc;
    }
}

// ---------------- kernel E: in-place BN apply + ReLU ----------------
__global__ void k_apply(float* __restrict__ y, const float* __restrict__ scl,
                        const float* __restrict__ shf) {
    int idx = blockIdx.x * 256 + threadIdx.x;          // float4 index
    int o = (idx >> 12) % OUTC_;
    float4 v = ((const float4*)y)[idx];
    float a = scl[o], b = shf[o];
    v.x = fmaxf(v.x * a + b, 0.f);
    v.y = fmaxf(v.y * a + b, 0.f);
    v.z = fmaxf(v.z * a + b, 0.f);
    v.w = fmaxf(v.w * a + b, 0.f);
    ((float4*)y)[idx] = v;
}

extern "C" void kernel_launch(void* const* d_in, const int* in_sizes, int n_in,
                              void* d_out, int out_size, void* d_ws, size_t ws_size,
                              hipStream_t stream) {
    const float* p_fea = (const float*)d_in[0];
    const float* p_seg = (const float*)d_in[1];
    const float* Wq    = (const float*)d_in[2];
    const float* bq    = (const float*)d_in[3];
    const float* Wk    = (const float*)d_in[4];
    const float* bk    = (const float*)d_in[5];
    const float* Wp    = (const float*)d_in[6];
    const float* gamma = (const float*)d_in[7];
    const float* beta  = (const float*)d_in[8];

    float* ws   = (float*)d_ws;
    float* pp   = ws + OFF_PP;
    float* dp   = ws + OFF_DP;
    float* eb   = ws + OFF_EB;
    float* wb16 = ws + OFF_WB16;
    float* m2b  = ws + OFF_M2B;
    float* part = ws + OFF_PART;
    float* scl  = ws + OFF_SCL;
    float* shf  = ws + OFF_SHF;
    float* ybuf = (float*)d_out;

    k_pool<<<512, 256, 0, stream>>>(p_fea, p_seg, pp, dp);
    k_center<<<64, 256, 0, stream>>>(pp, dp, Wq, bq, Wk, bk, Wp, eb, m2b, wb16);
    k_main<<<1024, 256, 0, stream>>>(p_fea, wb16, eb, m2b, ybuf, part);
    k_bn<<<1, 512, 0, stream>>>(part, gamma, beta, scl, shf);
    k_apply<<<(N_ * OUTC_ * S_ / 4) / 256, 256, 0, stream>>>(ybuf, scl, shf);
}